// Round 10
// baseline (6002.218 us; speedup 1.0000x reference)
//
#include <hip/hip_runtime.h>

#define BATCH 65536
#define T 500
#define STRIDE 36   // words per sample region in act LDS (16B-aligned, R3-proven)

typedef __attribute__((ext_vector_type(8))) short bf16x8;
typedef __attribute__((ext_vector_type(4))) float f32x4;
typedef __attribute__((ext_vector_type(2))) unsigned u32x2;

#define MFMA(A, B, C) __builtin_amdgcn_mfma_f32_16x16x32_bf16(A, B, C, 0, 0, 0)
#define PSEL 0x07060302u   // v_perm: low16 = hi16(srcB), high16 = hi16(srcA)

union U4 { unsigned u[4]; bf16x8 v; };

__device__ __forceinline__ float fast_tanh(float x) {
    // tanh = 1 - 2*rcp(exp(2x)+1); raw v_rcp_f32 (~1ulp) avoids div expansion
    float e = __expf(2.0f * x);
    return 1.0f - 2.0f * __builtin_amdgcn_rcpf(e + 1.0f);
}
__device__ __forceinline__ float fast_sp(float x) {
    float e = __expf(-fabsf(x));
    return fmaxf(x, 0.0f) + __logf(1.0f + e);
}

// truncation split: hi = trunc_bf16(x) (exact top-16), lo = trunc_bf16(x - hi).
__device__ __forceinline__ void tsplit(float x, short& hs, short& ls) {
    unsigned uh = __float_as_uint(x) & 0xFFFF0000u;
    float r = x - __uint_as_float(uh);
    hs = (short)(uh >> 16);
    ls = (short)(__float_as_uint(r) >> 16);
}

// ---- layer-1 merged A-fragment (k-packed hi/lo/bias, one MFMA per tile) ----
//  k0..k7  (G=0): wa_h wb_h b_h wa_h wb_h wa_h wb_h wa_l
//  k8..k11 (G=1): wb_l wa_l wb_l b_l
__device__ __forceinline__ void build_l1(const float* __restrict__ W,
                                         const float* __restrict__ Bv,
                                         int Mreal, int t, int lane, bf16x8& A) {
    int row = t * 16 + (lane & 15);
    int G = lane >> 4;
    float wa = 0.f, wb = 0.f, bi = 0.f;
    if (row < Mreal) { wa = W[2 * row]; wb = W[2 * row + 1]; bi = Bv[row]; }
    short wah, wal, wbh, wbl, bih, bil;
    tsplit(wa, wah, wal);
    tsplit(wb, wbh, wbl);
    tsplit(bi, bih, bil);
    #pragma unroll
    for (int j = 0; j < 8; ++j) A[j] = 0;
    if (G == 0) {
        A[0] = wah; A[1] = wbh; A[2] = bih; A[3] = wah;
        A[4] = wbh; A[5] = wah; A[6] = wbh; A[7] = wal;
    } else if (G == 1) {
        A[0] = wbl; A[1] = wal; A[2] = wbl; A[3] = bil;
    }
}

// ---- layer-2 A-fragment split, row-major W[M][K] ----
__device__ __forceinline__ void build_frag(const float* __restrict__ W,
                                           int Mreal, int Kreal, int Ks,
                                           int t, int u, int lane,
                                           bf16x8& hi, bf16x8& lo) {
    int row = t * 16 + (lane & 15);
    int kb = u * 32 + (lane >> 4) * 8;
    #pragma unroll
    for (int j = 0; j < 8; ++j) {
        int k = kb + j;
        float w = (row < Mreal && k < Kreal) ? W[row * Ks + k] : 0.0f;
        short hs, ls;
        tsplit(w, hs, ls);
        hi[j] = hs; lo[j] = ls;
    }
}

// tanh + trunc-split + LDS store
__device__ __forceinline__ void act_store_tanh(const f32x4* d,
                                               unsigned* ldsH, unsigned* ldsL,
                                               int cb, int G) {
    #pragma unroll
    for (int t = 0; t < 4; ++t) {
        float a0 = fast_tanh(d[t][0]);
        float a1 = fast_tanh(d[t][1]);
        float a2 = fast_tanh(d[t][2]);
        float a3 = fast_tanh(d[t][3]);
        unsigned u0 = __float_as_uint(a0), u1 = __float_as_uint(a1);
        unsigned u2 = __float_as_uint(a2), u3 = __float_as_uint(a3);
        unsigned h01 = __builtin_amdgcn_perm(u1, u0, PSEL);
        unsigned h23 = __builtin_amdgcn_perm(u3, u2, PSEL);
        float r0 = a0 - __uint_as_float(u0 & 0xFFFF0000u);
        float r1 = a1 - __uint_as_float(u1 & 0xFFFF0000u);
        float r2 = a2 - __uint_as_float(u2 & 0xFFFF0000u);
        float r3 = a3 - __uint_as_float(u3 & 0xFFFF0000u);
        unsigned l01 = __builtin_amdgcn_perm(__float_as_uint(r1), __float_as_uint(r0), PSEL);
        unsigned l23 = __builtin_amdgcn_perm(__float_as_uint(r3), __float_as_uint(r2), PSEL);
        int wo = cb + 8 * t + 2 * G;
        *reinterpret_cast<u32x2*>(&ldsH[wo]) = (u32x2){h01, h23};
        *reinterpret_cast<u32x2*>(&ldsL[wo]) = (u32x2){l01, l23};
    }
}

// y trunc 3-split -> k-packed B fragment (matches build_l1 k-slot table)
__device__ __forceinline__ void build_yB(float ya, float yb, int G, U4& yB) {
    unsigned ua = __float_as_uint(ya), ub = __float_as_uint(yb);
    unsigned uah = ua & 0xFFFF0000u;
    float ra = ya - __uint_as_float(uah);
    unsigned uam = __float_as_uint(ra) & 0xFFFF0000u;
    float ra2 = ra - __uint_as_float(uam);
    unsigned ubh = ub & 0xFFFF0000u;
    float rb = yb - __uint_as_float(ubh);
    unsigned ubm = __float_as_uint(rb) & 0xFFFF0000u;
    float rb2 = rb - __uint_as_float(ubm);

    unsigned w0g0 = __builtin_amdgcn_perm(ub, ua, PSEL);
    unsigned w1g0 = 0x00003F80u | uam;
    unsigned w2g0 = __builtin_amdgcn_perm(__float_as_uint(ra2), __float_as_uint(rb), PSEL);
    unsigned w3g0 = __builtin_amdgcn_perm(ua, __float_as_uint(rb2), PSEL);
    unsigned w0g1 = __builtin_amdgcn_perm(__float_as_uint(ra), ub, PSEL);
    unsigned w1g1 = (ubm >> 16) | 0x3F800000u;

    yB.u[0] = (G == 0) ? w0g0 : ((G == 1) ? w0g1 : 0u);
    yB.u[1] = (G == 0) ? w1g0 : ((G == 1) ? w1g1 : 0u);
    yB.u[2] = (G == 0) ? w2g0 : 0u;
    yB.u[3] = (G == 0) ? w3g0 : 0u;
}

__global__ void __launch_bounds__(256)
__attribute__((amdgpu_waves_per_eu(2, 2)))
node_kernel(const float* __restrict__ y0,
            const float* __restrict__ tt,
            const float* __restrict__ fw1, const float* __restrict__ fb1,
            const float* __restrict__ fw2, const float* __restrict__ fb2,
            const float* __restrict__ fw3, const float* __restrict__ fb3,
            const float* __restrict__ gw1, const float* __restrict__ gb1,
            const float* __restrict__ gw2, const float* __restrict__ gb2,
            const float* __restrict__ gw3, const float* __restrict__ gb3,
            float* __restrict__ out)
{
    // act buffers (per wave) + all weight fragments (shared per block)
    __shared__ __align__(16) unsigned lds_fhi[4][16 * STRIDE];
    __shared__ __align__(16) unsigned lds_flo[4][16 * STRIDE];
    __shared__ __align__(16) unsigned lds_ghi[4][16 * STRIDE];
    __shared__ __align__(16) unsigned lds_glo[4][16 * STRIDE];
    __shared__ float lds_y[4][2][16][2];
    __shared__ __align__(16) float lds_b2[2][64];            // f,g layer-2 bias
    __shared__ __align__(16) float lds_w3[4][64];            // f0,f1,g0,g1 rows
    __shared__ __align__(16) unsigned lds_l1[2][4][64 * 4];  // merged L1 frags
    __shared__ __align__(16) unsigned lds_w2h[2][8][64 * 4]; // L2 hi frags
    __shared__ __align__(16) unsigned lds_w2l[2][8][64 * 4]; // L2 lo frags
    // total approx 80 KB -> 2 blocks/CU

    const int lane  = threadIdx.x & 63;
    const int wIdx  = threadIdx.x >> 6;
    const int waveG = blockIdx.x * 4 + wIdx;
    const int c     = lane & 15;
    const int G     = lane >> 4;
    const bool lo16 = (lane < 16);
    const int cb    = c * STRIDE;
    const int lane4 = lane * 4;

    // block-shared tables
    if (threadIdx.x < 64) {
        int i = threadIdx.x;
        lds_b2[0][i] = fb2[i];
        lds_b2[1][i] = (i < 52) ? gb2[i] : 0.0f;
        lds_w3[0][i] = fw3[i];
        lds_w3[1][i] = fw3[64 + i];
        lds_w3[2][i] = (i < 52) ? gw3[i] : 0.0f;
        lds_w3[3][i] = (i < 52) ? gw3[52 + i] : 0.0f;
    }

    // ---- build all weight fragments into LDS (wave wIdx builds tile wIdx) ----
    {
        const int t = wIdx;
        bf16x8 A, hi, lo;
        build_l1(fw1, fb1, 64, t, lane, A);
        *reinterpret_cast<bf16x8*>(&lds_l1[0][t][lane4]) = A;
        build_l1(gw1, gb1, 52, t, lane, A);
        *reinterpret_cast<bf16x8*>(&lds_l1[1][t][lane4]) = A;
        #pragma unroll
        for (int u = 0; u < 2; ++u) {
            build_frag(fw2, 64, 64, 64, t, u, lane, hi, lo);
            *reinterpret_cast<bf16x8*>(&lds_w2h[0][2 * t + u][lane4]) = hi;
            *reinterpret_cast<bf16x8*>(&lds_w2l[0][2 * t + u][lane4]) = lo;
            build_frag(gw2, 52, 52, 52, t, u, lane, hi, lo);
            *reinterpret_cast<bf16x8*>(&lds_w2h[1][2 * t + u][lane4]) = hi;
            *reinterpret_cast<bf16x8*>(&lds_w2l[1][2 * t + u][lane4]) = lo;
        }
    }
    __syncthreads();

    const float dt = tt[1] - tt[0];
    const float b3a = fb3[0] + gb3[0];
    const float b3b = fb3[1] + gb3[1];
    const f32x4 zero4 = {0.f, 0.f, 0.f, 0.f};

    // ---- y0 init ----
    #pragma unroll 1
    for (int ct = 0; ct < 2; ++ct) {
        int sample = waveG * 32 + ct * 16 + c;
        if (lo16) {
            float2 yv = reinterpret_cast<const float2*>(y0)[sample];
            lds_y[wIdx][ct][c][0] = yv.x;
            lds_y[wIdx][ct][c][1] = yv.y;
            reinterpret_cast<float2*>(out)[sample] = yv;
        }
    }

    // ---- time loop: ct0/ct1 fused (weights read once), f-net then g-net ----
    #pragma unroll 1
    for (int s = 1; s < T; ++s) {
        // opaque zero index, redefined per iteration: blocks LICM/CSE from
        // hoisting weight-fragment loads into (spilled) registers.
        unsigned zoff = 0;
        asm volatile("" : "+v"(zoff));
        const unsigned z4 = zoff << 2;

        float ya0 = lds_y[wIdx][0][c][0];
        float yb0 = lds_y[wIdx][0][c][1];
        float ya1 = lds_y[wIdx][1][c][0];
        float yb1 = lds_y[wIdx][1][c][1];

        U4 yB0, yB1;
        build_yB(ya0, yb0, G, yB0);
        build_yB(ya1, yb1, G, yB1);

        float pa0 = 0.f, pb0 = 0.f, pa1 = 0.f, pb1 = 0.f;

        // ==================== f network ====================
        {
            // layer 1: A-frag read once, feeds both cts; d1 dies at act store
            f32x4 d0[4], d1[4];
            #pragma unroll
            for (int t = 0; t < 4; ++t) {
                bf16x8 A = *reinterpret_cast<const bf16x8*>(&lds_l1[0][t][lane4 + z4]);
                d0[t] = MFMA(A, yB0.v, zero4);
                d1[t] = MFMA(A, yB1.v, zero4);
            }
            bf16x8 H0[2], L0[2], H1[2], L1[2];
            act_store_tanh(d0, lds_fhi[wIdx], lds_flo[wIdx], cb, G);
            #pragma unroll
            for (int u = 0; u < 2; ++u) {
                int ro = cb + 16 * u + 4 * G;
                H0[u] = *reinterpret_cast<const bf16x8*>(&lds_fhi[wIdx][ro]);
                L0[u] = *reinterpret_cast<const bf16x8*>(&lds_flo[wIdx][ro]);
            }
            act_store_tanh(d1, lds_fhi[wIdx], lds_flo[wIdx], cb, G);
            #pragma unroll
            for (int u = 0; u < 2; ++u) {
                int ro = cb + 16 * u + 4 * G;
                H1[u] = *reinterpret_cast<const bf16x8*>(&lds_fhi[wIdx][ro]);
                L1[u] = *reinterpret_cast<const bf16x8*>(&lds_flo[wIdx][ro]);
            }
            // layer 2 + fused layer-3 epilogue per tile t (no d2 arrays)
            #pragma unroll
            for (int t = 0; t < 4; ++t) {
                f32x4 a0 = *reinterpret_cast<const f32x4*>(&lds_b2[0][16 * t + 4 * G + z4]);
                f32x4 a1 = a0;
                #pragma unroll
                for (int u = 0; u < 2; ++u) {
                    bf16x8 wh = *reinterpret_cast<const bf16x8*>(&lds_w2h[0][2 * t + u][lane4 + z4]);
                    bf16x8 wl = *reinterpret_cast<const bf16x8*>(&lds_w2l[0][2 * t + u][lane4 + z4]);
                    a0 = MFMA(wh, H0[u], a0);
                    a1 = MFMA(wh, H1[u], a1);
                    a0 = MFMA(wh, L0[u], a0);
                    a1 = MFMA(wh, L1[u], a1);
                    a0 = MFMA(wl, H0[u], a0);
                    a1 = MFMA(wl, H1[u], a1);
                }
                int fo = 16 * t + 4 * G + z4;
                f32x4 wf0 = *reinterpret_cast<const f32x4*>(&lds_w3[0][fo]);
                f32x4 wf1 = *reinterpret_cast<const f32x4*>(&lds_w3[1][fo]);
                #pragma unroll
                for (int r = 0; r < 4; ++r) {
                    float s0 = fast_sp(a0[r]);
                    pa0 = fmaf(wf0[r], s0, pa0);
                    pb0 = fmaf(wf1[r], s0, pb0);
                    float s1 = fast_sp(a1[r]);
                    pa1 = fmaf(wf0[r], s1, pa1);
                    pb1 = fmaf(wf1[r], s1, pb1);
                }
            }
        }

        // ==================== g network ====================
        {
            f32x4 d0[4], d1[4];
            #pragma unroll
            for (int t = 0; t < 4; ++t) {
                bf16x8 A = *reinterpret_cast<const bf16x8*>(&lds_l1[1][t][lane4 + z4]);
                d0[t] = MFMA(A, yB0.v, zero4);
                d1[t] = MFMA(A, yB1.v, zero4);
            }
            bf16x8 H0[2], L0[2], H1[2], L1[2];
            act_store_tanh(d0, lds_ghi[wIdx], lds_glo[wIdx], cb, G);
            #pragma unroll
            for (int u = 0; u < 2; ++u) {
                int ro = cb + 16 * u + 4 * G;
                H0[u] = *reinterpret_cast<const bf16x8*>(&lds_ghi[wIdx][ro]);
                L0[u] = *reinterpret_cast<const bf16x8*>(&lds_glo[wIdx][ro]);
            }
            act_store_tanh(d1, lds_ghi[wIdx], lds_glo[wIdx], cb, G);
            #pragma unroll
            for (int u = 0; u < 2; ++u) {
                int ro = cb + 16 * u + 4 * G;
                H1[u] = *reinterpret_cast<const bf16x8*>(&lds_ghi[wIdx][ro]);
                L1[u] = *reinterpret_cast<const bf16x8*>(&lds_glo[wIdx][ro]);
            }
            #pragma unroll
            for (int t = 0; t < 4; ++t) {
                f32x4 a0 = *reinterpret_cast<const f32x4*>(&lds_b2[1][16 * t + 4 * G + z4]);
                f32x4 a1 = a0;
                #pragma unroll
                for (int u = 0; u < 2; ++u) {
                    bf16x8 wh = *reinterpret_cast<const bf16x8*>(&lds_w2h[1][2 * t + u][lane4 + z4]);
                    bf16x8 wl = *reinterpret_cast<const bf16x8*>(&lds_w2l[1][2 * t + u][lane4 + z4]);
                    a0 = MFMA(wh, H0[u], a0);
                    a1 = MFMA(wh, H1[u], a1);
                    a0 = MFMA(wh, L0[u], a0);
                    a1 = MFMA(wh, L1[u], a1);
                    a0 = MFMA(wl, H0[u], a0);
                    a1 = MFMA(wl, H1[u], a1);
                }
                int fo = 16 * t + 4 * G + z4;
                f32x4 wg0 = *reinterpret_cast<const f32x4*>(&lds_w3[2][fo]);
                f32x4 wg1 = *reinterpret_cast<const f32x4*>(&lds_w3[3][fo]);
                #pragma unroll
                for (int r = 0; r < 4; ++r) {
                    float s0 = fast_sp(a0[r]);
                    pa0 = fmaf(wg0[r], s0, pa0);
                    pb0 = fmaf(wg1[r], s0, pb0);
                    float s1 = fast_sp(a1[r]);
                    pa1 = fmaf(wg0[r], s1, pa1);
                    pb1 = fmaf(wg1[r], s1, pb1);
                }
            }
        }

        pa0 += __shfl_xor(pa0, 16); pa0 += __shfl_xor(pa0, 32);
        pb0 += __shfl_xor(pb0, 16); pb0 += __shfl_xor(pb0, 32);
        pa1 += __shfl_xor(pa1, 16); pa1 += __shfl_xor(pa1, 32);
        pb1 += __shfl_xor(pb1, 16); pb1 += __shfl_xor(pb1, 32);

        // ---- Euler update + store (both cts) ----
        if (lo16) {
            float nya0 = fmaf(pa0 + b3a, dt, ya0);
            float nyb0 = fmaf(pb0 + b3b, dt, yb0);
            float nya1 = fmaf(pa1 + b3a, dt, ya1);
            float nyb1 = fmaf(pb1 + b3b, dt, yb1);
            lds_y[wIdx][0][c][0] = nya0;
            lds_y[wIdx][0][c][1] = nyb0;
            lds_y[wIdx][1][c][0] = nya1;
            lds_y[wIdx][1][c][1] = nyb1;
            int sample0 = waveG * 32 + c;
            reinterpret_cast<float2*>(out)[(size_t)s * BATCH + sample0] =
                make_float2(nya0, nyb0);
            reinterpret_cast<float2*>(out)[(size_t)s * BATCH + sample0 + 16] =
                make_float2(nya1, nyb1);
        }
    }
}

extern "C" void kernel_launch(void* const* d_in, const int* in_sizes, int n_in,
                              void* d_out, int out_size, void* d_ws, size_t ws_size,
                              hipStream_t stream) {
    const float* y0  = (const float*)d_in[0];
    const float* tt  = (const float*)d_in[1];
    const float* fw1 = (const float*)d_in[2];
    const float* fb1 = (const float*)d_in[3];
    const float* fw2 = (const float*)d_in[4];
    const float* fb2 = (const float*)d_in[5];
    const float* fw3 = (const float*)d_in[6];
    const float* fb3 = (const float*)d_in[7];
    const float* gw1 = (const float*)d_in[8];
    const float* gb1 = (const float*)d_in[9];
    const float* gw2 = (const float*)d_in[10];
    const float* gb2 = (const float*)d_in[11];
    const float* gw3 = (const float*)d_in[12];
    const float* gb3 = (const float*)d_in[13];
    float* out = (float*)d_out;

    dim3 grid(512);    // 2048 waves, 32 samples/wave -> 2 blocks/CU, 2 waves/SIMD
    dim3 block(256);
    hipLaunchKernelGGL(node_kernel, grid, block, 0, stream,
                       y0, tt, fw1, fb1, fw2, fb2, fw3, fb3,
                       gw1, gb1, gw2, gb2, gw3, gb3, out);
}

// Round 11
// 4441.716 us; speedup vs baseline: 1.3513x; 1.3513x over previous
//
#include <hip/hip_runtime.h>

#define BATCH 65536
#define T 500

typedef __attribute__((ext_vector_type(8))) short bf16x8;
typedef __attribute__((ext_vector_type(4))) float f32x4;

#define MFMA(A, B, C) __builtin_amdgcn_mfma_f32_16x16x32_bf16(A, B, C, 0, 0, 0)
#define PSEL 0x07060302u   // v_perm: low16 = hi16(srcB), high16 = hi16(srcA)

union U4 { unsigned u[4]; bf16x8 v; };

__device__ __forceinline__ float fast_tanh(float x) {
    // tanh = 1 - 2*rcp(exp(2x)+1); raw v_rcp_f32 (~1ulp) avoids div expansion
    float e = __expf(2.0f * x);
    return 1.0f - 2.0f * __builtin_amdgcn_rcpf(e + 1.0f);
}
__device__ __forceinline__ float fast_sp(float x) {
    float e = __expf(-fabsf(x));
    return fmaxf(x, 0.0f) + __logf(1.0f + e);
}

// truncation split: hi = trunc_bf16(x) (exact top-16), lo = trunc_bf16(x - hi).
__device__ __forceinline__ void tsplit(float x, short& hs, short& ls) {
    unsigned uh = __float_as_uint(x) & 0xFFFF0000u;
    float r = x - __uint_as_float(uh);
    hs = (short)(uh >> 16);
    ls = (short)(__float_as_uint(r) >> 16);
}

// ---- layer-1 merged A-fragment (k-packed hi/lo/bias, one MFMA per tile) ----
//  k0..k7  (G=0): wa_h wb_h b_h wa_h wb_h wa_h wb_h wa_l
//  k8..k11 (G=1): wb_l wa_l wb_l b_l
__device__ __forceinline__ void build_l1(const float* __restrict__ W,
                                         const float* __restrict__ Bv,
                                         int Mreal, int t, int lane, bf16x8& A) {
    int row = t * 16 + (lane & 15);
    int G = lane >> 4;
    float wa = 0.f, wb = 0.f, bi = 0.f;
    if (row < Mreal) { wa = W[2 * row]; wb = W[2 * row + 1]; bi = Bv[row]; }
    short wah, wal, wbh, wbl, bih, bil;
    tsplit(wa, wah, wal);
    tsplit(wb, wbh, wbl);
    tsplit(bi, bih, bil);
    #pragma unroll
    for (int j = 0; j < 8; ++j) A[j] = 0;
    if (G == 0) {
        A[0] = wah; A[1] = wbh; A[2] = bih; A[3] = wah;
        A[4] = wbh; A[5] = wah; A[6] = wbh; A[7] = wal;
    } else if (G == 1) {
        A[0] = wbl; A[1] = wal; A[2] = wbl; A[3] = bil;
    }
}

// ---- layer-2 A-fragment split with k-PERMUTED axis ----
// k-slot (u, G=lane>>4, j) holds hidden unit pi = 16*(2u + (j>>2)) + 4G + (j&3),
// so the D-registers of layer 1 (rows 16t+4G+r, t=2u+(j>>2)) ARE the B-frag:
// no cross-lane redistribution, no LDS act round-trip.
__device__ __forceinline__ void build_frag_pi(const float* __restrict__ W,
                                              int Mreal, int Kreal, int Ks,
                                              int t, int u, int lane,
                                              bf16x8& hi, bf16x8& lo) {
    int row = t * 16 + (lane & 15);
    int G = lane >> 4;
    #pragma unroll
    for (int j = 0; j < 8; ++j) {
        int hidden = 16 * (2 * u + (j >> 2)) + 4 * G + (j & 3);
        float w = (row < Mreal && hidden < Kreal) ? W[row * Ks + hidden] : 0.0f;
        short hs, ls;
        tsplit(w, hs, ls);
        hi[j] = hs; lo[j] = ls;
    }
}

// tanh + trunc-split, packed IN-REGISTER into B-fragments (H hi, L lo).
// Word order matches the pi-permuted W2 k-axis: H[t>>1].u[(t&1)*2 + {0,1}].
__device__ __forceinline__ void act_tanh_frags(const f32x4* d, U4* H, U4* L) {
    #pragma unroll
    for (int t = 0; t < 4; ++t) {
        float a0 = fast_tanh(d[t][0]);
        float a1 = fast_tanh(d[t][1]);
        float a2 = fast_tanh(d[t][2]);
        float a3 = fast_tanh(d[t][3]);
        unsigned u0 = __float_as_uint(a0), u1 = __float_as_uint(a1);
        unsigned u2 = __float_as_uint(a2), u3 = __float_as_uint(a3);
        unsigned h01 = __builtin_amdgcn_perm(u1, u0, PSEL);
        unsigned h23 = __builtin_amdgcn_perm(u3, u2, PSEL);
        float r0 = a0 - __uint_as_float(u0 & 0xFFFF0000u);
        float r1 = a1 - __uint_as_float(u1 & 0xFFFF0000u);
        float r2 = a2 - __uint_as_float(u2 & 0xFFFF0000u);
        float r3 = a3 - __uint_as_float(u3 & 0xFFFF0000u);
        unsigned l01 = __builtin_amdgcn_perm(__float_as_uint(r1), __float_as_uint(r0), PSEL);
        unsigned l23 = __builtin_amdgcn_perm(__float_as_uint(r3), __float_as_uint(r2), PSEL);
        H[t >> 1].u[(t & 1) * 2]     = h01;
        H[t >> 1].u[(t & 1) * 2 + 1] = h23;
        L[t >> 1].u[(t & 1) * 2]     = l01;
        L[t >> 1].u[(t & 1) * 2 + 1] = l23;
    }
}

// y trunc 3-split -> k-packed B fragment (matches build_l1 k-slot table)
__device__ __forceinline__ void build_yB(float ya, float yb, int G, U4& yB) {
    unsigned ua = __float_as_uint(ya), ub = __float_as_uint(yb);
    unsigned uah = ua & 0xFFFF0000u;
    float ra = ya - __uint_as_float(uah);
    unsigned uam = __float_as_uint(ra) & 0xFFFF0000u;
    float ra2 = ra - __uint_as_float(uam);
    unsigned ubh = ub & 0xFFFF0000u;
    float rb = yb - __uint_as_float(ubh);
    unsigned ubm = __float_as_uint(rb) & 0xFFFF0000u;
    float rb2 = rb - __uint_as_float(ubm);

    unsigned w0g0 = __builtin_amdgcn_perm(ub, ua, PSEL);
    unsigned w1g0 = 0x00003F80u | uam;
    unsigned w2g0 = __builtin_amdgcn_perm(__float_as_uint(ra2), __float_as_uint(rb), PSEL);
    unsigned w3g0 = __builtin_amdgcn_perm(ua, __float_as_uint(rb2), PSEL);
    unsigned w0g1 = __builtin_amdgcn_perm(__float_as_uint(ra), ub, PSEL);
    unsigned w1g1 = (ubm >> 16) | 0x3F800000u;

    yB.u[0] = (G == 0) ? w0g0 : ((G == 1) ? w0g1 : 0u);
    yB.u[1] = (G == 0) ? w1g0 : ((G == 1) ? w1g1 : 0u);
    yB.u[2] = (G == 0) ? w2g0 : 0u;
    yB.u[3] = (G == 0) ? w3g0 : 0u;
}

__global__ void __launch_bounds__(256)
__attribute__((amdgpu_waves_per_eu(2, 2)))
node_kernel(const float* __restrict__ y0,
            const float* __restrict__ tt,
            const float* __restrict__ fw1, const float* __restrict__ fb1,
            const float* __restrict__ fw2, const float* __restrict__ fb2,
            const float* __restrict__ fw3, const float* __restrict__ fb3,
            const float* __restrict__ gw1, const float* __restrict__ gb1,
            const float* __restrict__ gw2, const float* __restrict__ gb2,
            const float* __restrict__ gw3, const float* __restrict__ gb3,
            float* __restrict__ out)
{
    // all weight fragments shared per block; NO act buffers (in-register frags)
    __shared__ float lds_y[4][2][16][2];
    __shared__ __align__(16) float lds_b2[2][64];            // f,g layer-2 bias
    __shared__ __align__(16) float lds_w3[4][64];            // f0,f1,g0,g1 rows
    __shared__ __align__(16) unsigned lds_l1[2][4][64 * 4];  // merged L1 frags
    __shared__ __align__(16) unsigned lds_w2h[2][8][64 * 4]; // L2 hi frags (pi-k)
    __shared__ __align__(16) unsigned lds_w2l[2][8][64 * 4]; // L2 lo frags (pi-k)
    // total ~43 KB

    const int lane  = threadIdx.x & 63;
    const int wIdx  = threadIdx.x >> 6;
    const int waveG = blockIdx.x * 4 + wIdx;
    const int c     = lane & 15;
    const int G     = lane >> 4;
    const bool lo16 = (lane < 16);
    const int lane4 = lane * 4;

    // block-shared tables
    if (threadIdx.x < 64) {
        int i = threadIdx.x;
        lds_b2[0][i] = fb2[i];
        lds_b2[1][i] = (i < 52) ? gb2[i] : 0.0f;
        lds_w3[0][i] = fw3[i];
        lds_w3[1][i] = fw3[64 + i];
        lds_w3[2][i] = (i < 52) ? gw3[i] : 0.0f;
        lds_w3[3][i] = (i < 52) ? gw3[52 + i] : 0.0f;
    }

    // ---- build all weight fragments into LDS (wave wIdx builds tile wIdx) ----
    {
        const int t = wIdx;
        bf16x8 A, hi, lo;
        build_l1(fw1, fb1, 64, t, lane, A);
        *reinterpret_cast<bf16x8*>(&lds_l1[0][t][lane4]) = A;
        build_l1(gw1, gb1, 52, t, lane, A);
        *reinterpret_cast<bf16x8*>(&lds_l1[1][t][lane4]) = A;
        #pragma unroll
        for (int u = 0; u < 2; ++u) {
            build_frag_pi(fw2, 64, 64, 64, t, u, lane, hi, lo);
            *reinterpret_cast<bf16x8*>(&lds_w2h[0][2 * t + u][lane4]) = hi;
            *reinterpret_cast<bf16x8*>(&lds_w2l[0][2 * t + u][lane4]) = lo;
            build_frag_pi(gw2, 52, 52, 52, t, u, lane, hi, lo);
            *reinterpret_cast<bf16x8*>(&lds_w2h[1][2 * t + u][lane4]) = hi;
            *reinterpret_cast<bf16x8*>(&lds_w2l[1][2 * t + u][lane4]) = lo;
        }
    }
    __syncthreads();

    const float dt = tt[1] - tt[0];
    const float b3a = fb3[0] + gb3[0];
    const float b3b = fb3[1] + gb3[1];
    const f32x4 zero4 = {0.f, 0.f, 0.f, 0.f};

    // ---- y0 init ----
    #pragma unroll 1
    for (int ct = 0; ct < 2; ++ct) {
        int sample = waveG * 32 + ct * 16 + c;
        if (lo16) {
            float2 yv = reinterpret_cast<const float2*>(y0)[sample];
            lds_y[wIdx][ct][c][0] = yv.x;
            lds_y[wIdx][ct][c][1] = yv.y;
            reinterpret_cast<float2*>(out)[sample] = yv;
        }
    }

    // ---- time loop (R7 frame: unfused ct; weights from LDS; acts in regs) ----
    #pragma unroll 1
    for (int s = 1; s < T; ++s) {
        #pragma unroll 1
        for (int ct = 0; ct < 2; ++ct) {
            // opaque zero index, redefined per iteration: blocks LICM/CSE from
            // hoisting weight-fragment loads into (spilled) registers.
            unsigned zoff = 0;
            asm volatile("" : "+v"(zoff));
            const unsigned z4 = zoff << 2;

            float ya = lds_y[wIdx][ct][c][0];
            float yb = lds_y[wIdx][ct][c][1];

            U4 yB;
            build_yB(ya, yb, G, yB);

            float pa = 0.f, pb = 0.f;

            // ==================== f network ====================
            {
                f32x4 d[4];
                #pragma unroll
                for (int t = 0; t < 4; ++t) {
                    bf16x8 A = *reinterpret_cast<const bf16x8*>(&lds_l1[0][t][lane4 + z4]);
                    d[t] = MFMA(A, yB.v, zero4);
                }
                U4 H[2], L[2];
                act_tanh_frags(d, H, L);
                #pragma unroll
                for (int t = 0; t < 4; ++t) {
                    f32x4 a = *reinterpret_cast<const f32x4*>(&lds_b2[0][16 * t + 4 * G + z4]);
                    #pragma unroll
                    for (int u = 0; u < 2; ++u) {
                        bf16x8 wh = *reinterpret_cast<const bf16x8*>(&lds_w2h[0][2 * t + u][lane4 + z4]);
                        bf16x8 wl = *reinterpret_cast<const bf16x8*>(&lds_w2l[0][2 * t + u][lane4 + z4]);
                        a = MFMA(wh, H[u].v, a);
                        a = MFMA(wh, L[u].v, a);
                        a = MFMA(wl, H[u].v, a);
                    }
                    int fo = 16 * t + 4 * G + z4;
                    f32x4 wf0 = *reinterpret_cast<const f32x4*>(&lds_w3[0][fo]);
                    f32x4 wf1 = *reinterpret_cast<const f32x4*>(&lds_w3[1][fo]);
                    #pragma unroll
                    for (int r = 0; r < 4; ++r) {
                        float sv = fast_sp(a[r]);
                        pa = fmaf(wf0[r], sv, pa);
                        pb = fmaf(wf1[r], sv, pb);
                    }
                }
            }

            // ==================== g network ====================
            {
                f32x4 d[4];
                #pragma unroll
                for (int t = 0; t < 4; ++t) {
                    bf16x8 A = *reinterpret_cast<const bf16x8*>(&lds_l1[1][t][lane4 + z4]);
                    d[t] = MFMA(A, yB.v, zero4);
                }
                U4 H[2], L[2];
                act_tanh_frags(d, H, L);
                #pragma unroll
                for (int t = 0; t < 4; ++t) {
                    f32x4 a = *reinterpret_cast<const f32x4*>(&lds_b2[1][16 * t + 4 * G + z4]);
                    #pragma unroll
                    for (int u = 0; u < 2; ++u) {
                        bf16x8 wh = *reinterpret_cast<const bf16x8*>(&lds_w2h[1][2 * t + u][lane4 + z4]);
                        bf16x8 wl = *reinterpret_cast<const bf16x8*>(&lds_w2l[1][2 * t + u][lane4 + z4]);
                        a = MFMA(wh, H[u].v, a);
                        a = MFMA(wh, L[u].v, a);
                        a = MFMA(wl, H[u].v, a);
                    }
                    int fo = 16 * t + 4 * G + z4;
                    f32x4 wg0 = *reinterpret_cast<const f32x4*>(&lds_w3[2][fo]);
                    f32x4 wg1 = *reinterpret_cast<const f32x4*>(&lds_w3[3][fo]);
                    #pragma unroll
                    for (int r = 0; r < 4; ++r) {
                        float sv = fast_sp(a[r]);
                        pa = fmaf(wg0[r], sv, pa);
                        pb = fmaf(wg1[r], sv, pb);
                    }
                }
            }

            pa += __shfl_xor(pa, 16); pa += __shfl_xor(pa, 32);
            pb += __shfl_xor(pb, 16); pb += __shfl_xor(pb, 32);

            // ---- Euler update + store ----
            if (lo16) {
                float nya = fmaf(pa + b3a, dt, ya);
                float nyb = fmaf(pb + b3b, dt, yb);
                lds_y[wIdx][ct][c][0] = nya;
                lds_y[wIdx][ct][c][1] = nyb;
                int sample = waveG * 32 + ct * 16 + c;
                reinterpret_cast<float2*>(out)[(size_t)s * BATCH + sample] =
                    make_float2(nya, nyb);
            }
        }
    }
}

extern "C" void kernel_launch(void* const* d_in, const int* in_sizes, int n_in,
                              void* d_out, int out_size, void* d_ws, size_t ws_size,
                              hipStream_t stream) {
    const float* y0  = (const float*)d_in[0];
    const float* tt  = (const float*)d_in[1];
    const float* fw1 = (const float*)d_in[2];
    const float* fb1 = (const float*)d_in[3];
    const float* fw2 = (const float*)d_in[4];
    const float* fb2 = (const float*)d_in[5];
    const float* fw3 = (const float*)d_in[6];
    const float* fb3 = (const float*)d_in[7];
    const float* gw1 = (const float*)d_in[8];
    const float* gb1 = (const float*)d_in[9];
    const float* gw2 = (const float*)d_in[10];
    const float* gb2 = (const float*)d_in[11];
    const float* gw3 = (const float*)d_in[12];
    const float* gb3 = (const float*)d_in[13];
    float* out = (float*)d_out;

    dim3 grid(512);    // 2048 waves, 32 samples/wave -> 2 blocks/CU, 2 waves/SIMD
    dim3 block(256);
    hipLaunchKernelGGL(node_kernel, grid, block, 0, stream,
                       y0, tt, fw1, fb1, fw2, fb2, fw3, fb3,
                       gw1, gb1, gw2, gb2, gw3, gb3, out);
}

// Round 12
// 4110.232 us; speedup vs baseline: 1.4603x; 1.0806x over previous
//
#include <hip/hip_runtime.h>

#define BATCH 65536
#define T 500

typedef __attribute__((ext_vector_type(8))) short bf16x8;
typedef __attribute__((ext_vector_type(4))) float f32x4;

#define MFMA(A, B, C) __builtin_amdgcn_mfma_f32_16x16x32_bf16(A, B, C, 0, 0, 0)
#define PSEL 0x07060302u   // v_perm: low16 = hi16(srcB), high16 = hi16(srcA)

union U4 { unsigned u[4]; bf16x8 v; };

__device__ __forceinline__ float fast_tanh(float x) {
    // tanh = 1 - 2*rcp(exp(2x)+1); raw v_rcp_f32 (~1ulp) avoids div expansion
    float e = __expf(2.0f * x);
    return 1.0f - 2.0f * __builtin_amdgcn_rcpf(e + 1.0f);
}
__device__ __forceinline__ float fast_sp(float x) {
    float e = __expf(-fabsf(x));
    return fmaxf(x, 0.0f) + __logf(1.0f + e);
}

// truncation split: hi = trunc_bf16(x) (exact top-16), lo = trunc_bf16(x - hi).
__device__ __forceinline__ void tsplit(float x, short& hs, short& ls) {
    unsigned uh = __float_as_uint(x) & 0xFFFF0000u;
    float r = x - __uint_as_float(uh);
    hs = (short)(uh >> 16);
    ls = (short)(__float_as_uint(r) >> 16);
}

// ---- layer-1 merged A-fragment (k-packed hi/lo/bias, one MFMA per tile) ----
//  k0..k7  (G=0): wa_h wb_h b_h wa_h wb_h wa_h wb_h wa_l
//  k8..k11 (G=1): wb_l wa_l wb_l b_l
__device__ __forceinline__ void build_l1(const float* __restrict__ W,
                                         const float* __restrict__ Bv,
                                         int Mreal, int t, int lane, bf16x8& A) {
    int row = t * 16 + (lane & 15);
    int G = lane >> 4;
    float wa = 0.f, wb = 0.f, bi = 0.f;
    if (row < Mreal) { wa = W[2 * row]; wb = W[2 * row + 1]; bi = Bv[row]; }
    short wah, wal, wbh, wbl, bih, bil;
    tsplit(wa, wah, wal);
    tsplit(wb, wbh, wbl);
    tsplit(bi, bih, bil);
    #pragma unroll
    for (int j = 0; j < 8; ++j) A[j] = 0;
    if (G == 0) {
        A[0] = wah; A[1] = wbh; A[2] = bih; A[3] = wah;
        A[4] = wbh; A[5] = wah; A[6] = wbh; A[7] = wal;
    } else if (G == 1) {
        A[0] = wbl; A[1] = wal; A[2] = wbl; A[3] = bil;
    }
}

// ---- layer-2 A-fragment split with k-PERMUTED axis ----
// k-slot (u, G=lane>>4, j) holds hidden unit pi = 16*(2u + (j>>2)) + 4G + (j&3),
// so the D-registers of layer 1 (rows 16t+4G+r, t=2u+(j>>2)) ARE the B-frag:
// no cross-lane redistribution, no LDS act round-trip.
__device__ __forceinline__ void build_frag_pi(const float* __restrict__ W,
                                              int Mreal, int Kreal, int Ks,
                                              int t, int u, int lane,
                                              bf16x8& hi, bf16x8& lo) {
    int row = t * 16 + (lane & 15);
    int G = lane >> 4;
    #pragma unroll
    for (int j = 0; j < 8; ++j) {
        int hidden = 16 * (2 * u + (j >> 2)) + 4 * G + (j & 3);
        float w = (row < Mreal && hidden < Kreal) ? W[row * Ks + hidden] : 0.0f;
        short hs, ls;
        tsplit(w, hs, ls);
        hi[j] = hs; lo[j] = ls;
    }
}

// tanh + trunc-split, packed IN-REGISTER into B-fragments (H hi, L lo).
// Word order matches the pi-permuted W2 k-axis: H[t>>1].u[(t&1)*2 + {0,1}].
__device__ __forceinline__ void act_tanh_frags(const f32x4* d, U4* H, U4* L) {
    #pragma unroll
    for (int t = 0; t < 4; ++t) {
        float a0 = fast_tanh(d[t][0]);
        float a1 = fast_tanh(d[t][1]);
        float a2 = fast_tanh(d[t][2]);
        float a3 = fast_tanh(d[t][3]);
        unsigned u0 = __float_as_uint(a0), u1 = __float_as_uint(a1);
        unsigned u2 = __float_as_uint(a2), u3 = __float_as_uint(a3);
        unsigned h01 = __builtin_amdgcn_perm(u1, u0, PSEL);
        unsigned h23 = __builtin_amdgcn_perm(u3, u2, PSEL);
        float r0 = a0 - __uint_as_float(u0 & 0xFFFF0000u);
        float r1 = a1 - __uint_as_float(u1 & 0xFFFF0000u);
        float r2 = a2 - __uint_as_float(u2 & 0xFFFF0000u);
        float r3 = a3 - __uint_as_float(u3 & 0xFFFF0000u);
        unsigned l01 = __builtin_amdgcn_perm(__float_as_uint(r1), __float_as_uint(r0), PSEL);
        unsigned l23 = __builtin_amdgcn_perm(__float_as_uint(r3), __float_as_uint(r2), PSEL);
        H[t >> 1].u[(t & 1) * 2]     = h01;
        H[t >> 1].u[(t & 1) * 2 + 1] = h23;
        L[t >> 1].u[(t & 1) * 2]     = l01;
        L[t >> 1].u[(t & 1) * 2 + 1] = l23;
    }
}

// y trunc 3-split -> k-packed B fragment (matches build_l1 k-slot table)
__device__ __forceinline__ void build_yB(float ya, float yb, int G, U4& yB) {
    unsigned ua = __float_as_uint(ya), ub = __float_as_uint(yb);
    unsigned uah = ua & 0xFFFF0000u;
    float ra = ya - __uint_as_float(uah);
    unsigned uam = __float_as_uint(ra) & 0xFFFF0000u;
    float ra2 = ra - __uint_as_float(uam);
    unsigned ubh = ub & 0xFFFF0000u;
    float rb = yb - __uint_as_float(ubh);
    unsigned ubm = __float_as_uint(rb) & 0xFFFF0000u;
    float rb2 = rb - __uint_as_float(ubm);

    unsigned w0g0 = __builtin_amdgcn_perm(ub, ua, PSEL);
    unsigned w1g0 = 0x00003F80u | uam;
    unsigned w2g0 = __builtin_amdgcn_perm(__float_as_uint(ra2), __float_as_uint(rb), PSEL);
    unsigned w3g0 = __builtin_amdgcn_perm(ua, __float_as_uint(rb2), PSEL);
    unsigned w0g1 = __builtin_amdgcn_perm(__float_as_uint(ra), ub, PSEL);
    unsigned w1g1 = (ubm >> 16) | 0x3F800000u;

    yB.u[0] = (G == 0) ? w0g0 : ((G == 1) ? w0g1 : 0u);
    yB.u[1] = (G == 0) ? w1g0 : ((G == 1) ? w1g1 : 0u);
    yB.u[2] = (G == 0) ? w2g0 : 0u;
    yB.u[3] = (G == 0) ? w3g0 : 0u;
}

__global__ void __launch_bounds__(512)
__attribute__((amdgpu_waves_per_eu(4, 4)))
node_kernel(const float* __restrict__ y0,
            const float* __restrict__ tt,
            const float* __restrict__ fw1, const float* __restrict__ fb1,
            const float* __restrict__ fw2, const float* __restrict__ fb2,
            const float* __restrict__ fw3, const float* __restrict__ fb3,
            const float* __restrict__ gw1, const float* __restrict__ gb1,
            const float* __restrict__ gw2, const float* __restrict__ gb2,
            const float* __restrict__ gw3, const float* __restrict__ gb3,
            float* __restrict__ out)
{
    // all weight fragments shared per block; acts live in registers
    __shared__ float lds_y[8][16][2];
    __shared__ __align__(16) float lds_b2[2][64];            // f,g layer-2 bias
    __shared__ __align__(16) float lds_w3[4][64];            // f0,f1,g0,g1 rows
    __shared__ __align__(16) unsigned lds_l1[2][4][64 * 4];  // merged L1 frags
    __shared__ __align__(16) unsigned lds_w2h[2][8][64 * 4]; // L2 hi frags (pi-k)
    __shared__ __align__(16) unsigned lds_w2l[2][8][64 * 4]; // L2 lo frags (pi-k)
    // total ~43.5 KB -> 2 blocks/CU (87 KB), 16 waves/CU = 4 waves/SIMD

    const int lane  = threadIdx.x & 63;
    const int wIdx  = threadIdx.x >> 6;          // 0..7
    const int waveG = blockIdx.x * 8 + wIdx;     // 4096 waves
    const int c     = lane & 15;
    const int G     = lane >> 4;
    const bool lo16 = (lane < 16);
    const int lane4 = lane * 4;

    // block-shared tables
    if (threadIdx.x < 64) {
        int i = threadIdx.x;
        lds_b2[0][i] = fb2[i];
        lds_b2[1][i] = (i < 52) ? gb2[i] : 0.0f;
        lds_w3[0][i] = fw3[i];
        lds_w3[1][i] = fw3[64 + i];
        lds_w3[2][i] = (i < 52) ? gw3[i] : 0.0f;
        lds_w3[3][i] = (i < 52) ? gw3[52 + i] : 0.0f;
    }

    // ---- build all weight fragments into LDS (waves 0-3 build tile wIdx) ----
    if (wIdx < 4) {
        const int t = wIdx;
        bf16x8 A, hi, lo;
        build_l1(fw1, fb1, 64, t, lane, A);
        *reinterpret_cast<bf16x8*>(&lds_l1[0][t][lane4]) = A;
        build_l1(gw1, gb1, 52, t, lane, A);
        *reinterpret_cast<bf16x8*>(&lds_l1[1][t][lane4]) = A;
        #pragma unroll
        for (int u = 0; u < 2; ++u) {
            build_frag_pi(fw2, 64, 64, 64, t, u, lane, hi, lo);
            *reinterpret_cast<bf16x8*>(&lds_w2h[0][2 * t + u][lane4]) = hi;
            *reinterpret_cast<bf16x8*>(&lds_w2l[0][2 * t + u][lane4]) = lo;
            build_frag_pi(gw2, 52, 52, 52, t, u, lane, hi, lo);
            *reinterpret_cast<bf16x8*>(&lds_w2h[1][2 * t + u][lane4]) = hi;
            *reinterpret_cast<bf16x8*>(&lds_w2l[1][2 * t + u][lane4]) = lo;
        }
    }
    __syncthreads();

    const float dt = tt[1] - tt[0];
    const float b3a = fb3[0] + gb3[0];
    const float b3b = fb3[1] + gb3[1];
    const f32x4 zero4 = {0.f, 0.f, 0.f, 0.f};

    // ---- y0 init (16 samples per wave) ----
    {
        int sample = waveG * 16 + c;
        if (lo16) {
            float2 yv = reinterpret_cast<const float2*>(y0)[sample];
            lds_y[wIdx][c][0] = yv.x;
            lds_y[wIdx][c][1] = yv.y;
            reinterpret_cast<float2*>(out)[sample] = yv;
        }
    }

    // ---- time loop: one sample-group per wave; weights from LDS; acts in regs
    #pragma unroll 1
    for (int s = 1; s < T; ++s) {
        // opaque zero index, redefined per iteration: blocks LICM/CSE from
        // hoisting weight-fragment loads into (spilled) registers.
        unsigned zoff = 0;
        asm volatile("" : "+v"(zoff));
        const unsigned z4 = zoff << 2;

        float ya = lds_y[wIdx][c][0];
        float yb = lds_y[wIdx][c][1];

        U4 yB;
        build_yB(ya, yb, G, yB);

        float pa = 0.f, pb = 0.f;

        // ==================== f network ====================
        {
            f32x4 d[4];
            #pragma unroll
            for (int t = 0; t < 4; ++t) {
                bf16x8 A = *reinterpret_cast<const bf16x8*>(&lds_l1[0][t][lane4 + z4]);
                d[t] = MFMA(A, yB.v, zero4);
            }
            U4 H[2], L[2];
            act_tanh_frags(d, H, L);
            #pragma unroll
            for (int t = 0; t < 4; ++t) {
                f32x4 a = *reinterpret_cast<const f32x4*>(&lds_b2[0][16 * t + 4 * G + z4]);
                #pragma unroll
                for (int u = 0; u < 2; ++u) {
                    bf16x8 wh = *reinterpret_cast<const bf16x8*>(&lds_w2h[0][2 * t + u][lane4 + z4]);
                    bf16x8 wl = *reinterpret_cast<const bf16x8*>(&lds_w2l[0][2 * t + u][lane4 + z4]);
                    a = MFMA(wh, H[u].v, a);
                    a = MFMA(wh, L[u].v, a);
                    a = MFMA(wl, H[u].v, a);
                }
                int fo = 16 * t + 4 * G + z4;
                f32x4 wf0 = *reinterpret_cast<const f32x4*>(&lds_w3[0][fo]);
                f32x4 wf1 = *reinterpret_cast<const f32x4*>(&lds_w3[1][fo]);
                #pragma unroll
                for (int r = 0; r < 4; ++r) {
                    float sv = fast_sp(a[r]);
                    pa = fmaf(wf0[r], sv, pa);
                    pb = fmaf(wf1[r], sv, pb);
                }
            }
        }

        // ==================== g network ====================
        {
            f32x4 d[4];
            #pragma unroll
            for (int t = 0; t < 4; ++t) {
                bf16x8 A = *reinterpret_cast<const bf16x8*>(&lds_l1[1][t][lane4 + z4]);
                d[t] = MFMA(A, yB.v, zero4);
            }
            U4 H[2], L[2];
            act_tanh_frags(d, H, L);
            #pragma unroll
            for (int t = 0; t < 4; ++t) {
                f32x4 a = *reinterpret_cast<const f32x4*>(&lds_b2[1][16 * t + 4 * G + z4]);
                #pragma unroll
                for (int u = 0; u < 2; ++u) {
                    bf16x8 wh = *reinterpret_cast<const bf16x8*>(&lds_w2h[1][2 * t + u][lane4 + z4]);
                    bf16x8 wl = *reinterpret_cast<const bf16x8*>(&lds_w2l[1][2 * t + u][lane4 + z4]);
                    a = MFMA(wh, H[u].v, a);
                    a = MFMA(wh, L[u].v, a);
                    a = MFMA(wl, H[u].v, a);
                }
                int fo = 16 * t + 4 * G + z4;
                f32x4 wg0 = *reinterpret_cast<const f32x4*>(&lds_w3[2][fo]);
                f32x4 wg1 = *reinterpret_cast<const f32x4*>(&lds_w3[3][fo]);
                #pragma unroll
                for (int r = 0; r < 4; ++r) {
                    float sv = fast_sp(a[r]);
                    pa = fmaf(wg0[r], sv, pa);
                    pb = fmaf(wg1[r], sv, pb);
                }
            }
        }

        pa += __shfl_xor(pa, 16); pa += __shfl_xor(pa, 32);
        pb += __shfl_xor(pb, 16); pb += __shfl_xor(pb, 32);

        // ---- Euler update + store ----
        if (lo16) {
            float nya = fmaf(pa + b3a, dt, ya);
            float nyb = fmaf(pb + b3b, dt, yb);
            lds_y[wIdx][c][0] = nya;
            lds_y[wIdx][c][1] = nyb;
            int sample = waveG * 16 + c;
            reinterpret_cast<float2*>(out)[(size_t)s * BATCH + sample] =
                make_float2(nya, nyb);
        }
    }
}

extern "C" void kernel_launch(void* const* d_in, const int* in_sizes, int n_in,
                              void* d_out, int out_size, void* d_ws, size_t ws_size,
                              hipStream_t stream) {
    const float* y0  = (const float*)d_in[0];
    const float* tt  = (const float*)d_in[1];
    const float* fw1 = (const float*)d_in[2];
    const float* fb1 = (const float*)d_in[3];
    const float* fw2 = (const float*)d_in[4];
    const float* fb2 = (const float*)d_in[5];
    const float* fw3 = (const float*)d_in[6];
    const float* fb3 = (const float*)d_in[7];
    const float* gw1 = (const float*)d_in[8];
    const float* gb1 = (const float*)d_in[9];
    const float* gw2 = (const float*)d_in[10];
    const float* gb2 = (const float*)d_in[11];
    const float* gw3 = (const float*)d_in[12];
    const float* gb3 = (const float*)d_in[13];
    float* out = (float*)d_out;

    dim3 grid(512);    // 512 blocks x 8 waves = 4096 waves, 16 samples/wave
    dim3 block(512);   // 2 blocks/CU -> 16 waves/CU = 4 waves/SIMD
    hipLaunchKernelGGL(node_kernel, grid, block, 0, stream,
                       y0, tt, fw1, fb1, fw2, fb2, fw3, fb3,
                       gw1, gb1, gw2, gb2, gw3, gb3, out);
}

// Round 13
// 3512.873 us; speedup vs baseline: 1.7086x; 1.1700x over previous
//
#include <hip/hip_runtime.h>

#define BATCH 65536
#define T 500

typedef __attribute__((ext_vector_type(8))) short bf16x8;
typedef __attribute__((ext_vector_type(4))) float f32x4;

#define MFMA(A, B, C) __builtin_amdgcn_mfma_f32_16x16x32_bf16(A, B, C, 0, 0, 0)
#define PSEL 0x07060302u   // v_perm: low16 = hi16(srcB), high16 = hi16(srcA)

union U4 { unsigned u[4]; bf16x8 v; };

__device__ __forceinline__ float fast_tanh(float x) {
    // tanh = 1 - 2*rcp(exp(2x)+1); raw v_rcp_f32 (~1ulp) avoids div expansion
    float e = __expf(2.0f * x);
    return 1.0f - 2.0f * __builtin_amdgcn_rcpf(e + 1.0f);
}
__device__ __forceinline__ float fast_sp(float x) {
    float e = __expf(-fabsf(x));
    return fmaxf(x, 0.0f) + __logf(1.0f + e);
}

// truncation split: hi = trunc_bf16(x) (exact top-16), lo = trunc_bf16(x - hi).
__device__ __forceinline__ void tsplit(float x, short& hs, short& ls) {
    unsigned uh = __float_as_uint(x) & 0xFFFF0000u;
    float r = x - __uint_as_float(uh);
    hs = (short)(uh >> 16);
    ls = (short)(__float_as_uint(r) >> 16);
}

// ---- layer-1 merged A-fragment (k-packed hi/lo/bias, one MFMA per tile) ----
//  k0..k7  (G=0): wa_h wb_h b_h wa_h wb_h wa_h wb_h wa_l
//  k8..k11 (G=1): wb_l wa_l wb_l b_l
__device__ __forceinline__ void build_l1(const float* __restrict__ W,
                                         const float* __restrict__ Bv,
                                         int Mreal, int t, int lane, bf16x8& A) {
    int row = t * 16 + (lane & 15);
    int G = lane >> 4;
    float wa = 0.f, wb = 0.f, bi = 0.f;
    if (row < Mreal) { wa = W[2 * row]; wb = W[2 * row + 1]; bi = Bv[row]; }
    short wah, wal, wbh, wbl, bih, bil;
    tsplit(wa, wah, wal);
    tsplit(wb, wbh, wbl);
    tsplit(bi, bih, bil);
    #pragma unroll
    for (int j = 0; j < 8; ++j) A[j] = 0;
    if (G == 0) {
        A[0] = wah; A[1] = wbh; A[2] = bih; A[3] = wah;
        A[4] = wbh; A[5] = wah; A[6] = wbh; A[7] = wal;
    } else if (G == 1) {
        A[0] = wbl; A[1] = wal; A[2] = wbl; A[3] = bil;
    }
}

// ---- A-fragment split with k-PERMUTED axis ----
// k-slot (u, G=lane>>4, j) holds hidden unit pi = 16*(2u + (j>>2)) + 4G + (j&3),
// so the D-registers of the previous layer ARE the B-frag (no redistribution).
__device__ __forceinline__ void build_frag_pi(const float* __restrict__ W,
                                              int Mreal, int Kreal, int Ks,
                                              int t, int u, int lane,
                                              bf16x8& hi, bf16x8& lo) {
    int row = t * 16 + (lane & 15);
    int G = lane >> 4;
    #pragma unroll
    for (int j = 0; j < 8; ++j) {
        int hidden = 16 * (2 * u + (j >> 2)) + 4 * G + (j & 3);
        float w = (row < Mreal && hidden < Kreal) ? W[row * Ks + hidden] : 0.0f;
        short hs, ls;
        tsplit(w, hs, ls);
        hi[j] = hs; lo[j] = ls;
    }
}

// activation + trunc-bf16 pack of two D-tiles (2u, 2u+1) into one B k-frag.
template<bool TANH>
__device__ __forceinline__ U4 act_pack2(f32x4 dA, f32x4 dB) {
    float a0 = TANH ? fast_tanh(dA[0]) : fast_sp(dA[0]);
    float a1 = TANH ? fast_tanh(dA[1]) : fast_sp(dA[1]);
    float a2 = TANH ? fast_tanh(dA[2]) : fast_sp(dA[2]);
    float a3 = TANH ? fast_tanh(dA[3]) : fast_sp(dA[3]);
    float b0 = TANH ? fast_tanh(dB[0]) : fast_sp(dB[0]);
    float b1 = TANH ? fast_tanh(dB[1]) : fast_sp(dB[1]);
    float b2 = TANH ? fast_tanh(dB[2]) : fast_sp(dB[2]);
    float b3 = TANH ? fast_tanh(dB[3]) : fast_sp(dB[3]);
    U4 r;
    r.u[0] = __builtin_amdgcn_perm(__float_as_uint(a1), __float_as_uint(a0), PSEL);
    r.u[1] = __builtin_amdgcn_perm(__float_as_uint(a3), __float_as_uint(a2), PSEL);
    r.u[2] = __builtin_amdgcn_perm(__float_as_uint(b1), __float_as_uint(b0), PSEL);
    r.u[3] = __builtin_amdgcn_perm(__float_as_uint(b3), __float_as_uint(b2), PSEL);
    return r;
}

// y trunc 3-split -> k-packed B fragment (matches build_l1 k-slot table)
__device__ __forceinline__ void build_yB(float ya, float yb, int G, U4& yB) {
    unsigned ua = __float_as_uint(ya), ub = __float_as_uint(yb);
    unsigned uah = ua & 0xFFFF0000u;
    float ra = ya - __uint_as_float(uah);
    unsigned uam = __float_as_uint(ra) & 0xFFFF0000u;
    float ra2 = ra - __uint_as_float(uam);
    unsigned ubh = ub & 0xFFFF0000u;
    float rb = yb - __uint_as_float(ubh);
    unsigned ubm = __float_as_uint(rb) & 0xFFFF0000u;
    float rb2 = rb - __uint_as_float(ubm);

    unsigned w0g0 = __builtin_amdgcn_perm(ub, ua, PSEL);
    unsigned w1g0 = 0x00003F80u | uam;
    unsigned w2g0 = __builtin_amdgcn_perm(__float_as_uint(ra2), __float_as_uint(rb), PSEL);
    unsigned w3g0 = __builtin_amdgcn_perm(ua, __float_as_uint(rb2), PSEL);
    unsigned w0g1 = __builtin_amdgcn_perm(__float_as_uint(ra), ub, PSEL);
    unsigned w1g1 = (ubm >> 16) | 0x3F800000u;

    yB.u[0] = (G == 0) ? w0g0 : ((G == 1) ? w0g1 : 0u);
    yB.u[1] = (G == 0) ? w1g0 : ((G == 1) ? w1g1 : 0u);
    yB.u[2] = (G == 0) ? w2g0 : 0u;
    yB.u[3] = (G == 0) ? w3g0 : 0u;
}

__global__ void __launch_bounds__(512)
__attribute__((amdgpu_waves_per_eu(4, 4)))
node_kernel(const float* __restrict__ y0,
            const float* __restrict__ tt,
            const float* __restrict__ fw1, const float* __restrict__ fb1,
            const float* __restrict__ fw2, const float* __restrict__ fb2,
            const float* __restrict__ fw3, const float* __restrict__ fb3,
            const float* __restrict__ gw1, const float* __restrict__ gb1,
            const float* __restrict__ gw2, const float* __restrict__ gb2,
            const float* __restrict__ gw3, const float* __restrict__ gb3,
            float* __restrict__ out)
{
    // all weight fragments shared per block; acts live in registers
    __shared__ float lds_y[8][16][2];
    __shared__ __align__(16) float lds_b2[2][64];            // f,g layer-2 bias
    __shared__ __align__(16) unsigned lds_l1[2][4][256];     // merged L1 frags
    __shared__ __align__(16) unsigned lds_w2h[2][8][256];    // L2 hi frags (pi-k)
    __shared__ __align__(16) unsigned lds_w2l[2][8][256];    // L2 lo frags (pi-k)
    __shared__ __align__(16) unsigned lds_w3A[2][2][256];    // L3 hi frags (pi-k)
    // total ~49.5 KB -> 2 blocks/CU, 16 waves/CU = 4 waves/SIMD

    const int lane  = threadIdx.x & 63;
    const int wIdx  = threadIdx.x >> 6;          // 0..7
    const int waveG = blockIdx.x * 8 + wIdx;     // 4096 waves
    const int c     = lane & 15;
    const int G     = lane >> 4;
    const bool lo16 = (lane < 16);
    const int lane4 = lane * 4;

    // block-shared tables
    if (threadIdx.x < 64) {
        int i = threadIdx.x;
        lds_b2[0][i] = fb2[i];
        lds_b2[1][i] = (i < 52) ? gb2[i] : 0.0f;
    }

    // ---- build all weight fragments into LDS ----
    if (wIdx < 4) {
        const int t = wIdx;
        bf16x8 A, hi, lo;
        build_l1(fw1, fb1, 64, t, lane, A);
        *reinterpret_cast<bf16x8*>(&lds_l1[0][t][lane4]) = A;
        build_l1(gw1, gb1, 52, t, lane, A);
        *reinterpret_cast<bf16x8*>(&lds_l1[1][t][lane4]) = A;
        #pragma unroll
        for (int u = 0; u < 2; ++u) {
            build_frag_pi(fw2, 64, 64, 64, t, u, lane, hi, lo);
            *reinterpret_cast<bf16x8*>(&lds_w2h[0][2 * t + u][lane4]) = hi;
            *reinterpret_cast<bf16x8*>(&lds_w2l[0][2 * t + u][lane4]) = lo;
            build_frag_pi(gw2, 52, 52, 52, t, u, lane, hi, lo);
            *reinterpret_cast<bf16x8*>(&lds_w2h[1][2 * t + u][lane4]) = hi;
            *reinterpret_cast<bf16x8*>(&lds_w2l[1][2 * t + u][lane4]) = lo;
        }
    } else {
        const int net = (wIdx - 4) >> 1;         // 0=f, 1=g
        const int u   = (wIdx - 4) & 1;
        bf16x8 hi, lo;
        build_frag_pi(net ? gw3 : fw3, 2, net ? 52 : 64, net ? 52 : 64,
                      0, u, lane, hi, lo);
        *reinterpret_cast<bf16x8*>(&lds_w3A[net][u][lane4]) = hi;
    }
    __syncthreads();

    const float dt = tt[1] - tt[0];
    const float b3a = fb3[0] + gb3[0];
    const float b3b = fb3[1] + gb3[1];
    const f32x4 zero4 = {0.f, 0.f, 0.f, 0.f};

    // ---- y0 init (16 samples per wave) ----
    {
        int sample = waveG * 16 + c;
        if (lo16) {
            float2 yv = reinterpret_cast<const float2*>(y0)[sample];
            lds_y[wIdx][c][0] = yv.x;
            lds_y[wIdx][c][1] = yv.y;
            reinterpret_cast<float2*>(out)[sample] = yv;
        }
    }

    // ---- time loop ----
    #pragma unroll 1
    for (int s = 1; s < T; ++s) {
        // opaque zero index, redefined per iteration: blocks LICM/CSE from
        // hoisting weight-fragment loads into (spilled) registers.
        unsigned zoff = 0;
        asm volatile("" : "+v"(zoff));
        const unsigned z4 = zoff << 2;

        float ya = lds_y[wIdx][c][0];
        float yb = lds_y[wIdx][c][1];

        U4 yB;
        build_yB(ya, yb, G, yB);

        // layer-3 accumulator: D row 0 = out dim a, row 1 = out dim b (G==0)
        f32x4 acc3;
        acc3[0] = lo16 ? b3a : 0.f;
        acc3[1] = lo16 ? b3b : 0.f;
        acc3[2] = 0.f;
        acc3[3] = 0.f;

        #pragma unroll
        for (int net = 0; net < 2; ++net) {
            // layer 1: one MFMA per tile
            f32x4 d0, d1, d2, d3;
            {
                bf16x8 A0 = *reinterpret_cast<const bf16x8*>(&lds_l1[net][0][lane4 + z4]);
                bf16x8 A1 = *reinterpret_cast<const bf16x8*>(&lds_l1[net][1][lane4 + z4]);
                bf16x8 A2 = *reinterpret_cast<const bf16x8*>(&lds_l1[net][2][lane4 + z4]);
                bf16x8 A3 = *reinterpret_cast<const bf16x8*>(&lds_l1[net][3][lane4 + z4]);
                d0 = MFMA(A0, yB.v, zero4);
                d1 = MFMA(A1, yB.v, zero4);
                d2 = MFMA(A2, yB.v, zero4);
                d3 = MFMA(A3, yB.v, zero4);
            }
            U4 H0 = act_pack2<true>(d0, d1);
            U4 H1 = act_pack2<true>(d2, d3);

            // layer 2 (wh*H + wl*H) + layer-3 MFMA epilogue per half
            #pragma unroll
            for (int half = 0; half < 2; ++half) {
                f32x4 e[2];
                #pragma unroll
                for (int k = 0; k < 2; ++k) {
                    int t = 2 * half + k;
                    f32x4 a = *reinterpret_cast<const f32x4*>(&lds_b2[net][16 * t + 4 * G + z4]);
                    #pragma unroll
                    for (int u = 0; u < 2; ++u) {
                        bf16x8 wh = *reinterpret_cast<const bf16x8*>(&lds_w2h[net][2 * t + u][lane4 + z4]);
                        bf16x8 wl = *reinterpret_cast<const bf16x8*>(&lds_w2l[net][2 * t + u][lane4 + z4]);
                        a = MFMA(wh, u ? H1.v : H0.v, a);
                        a = MFMA(wl, u ? H1.v : H0.v, a);
                    }
                    e[k] = a;
                }
                U4 S = act_pack2<false>(e[0], e[1]);
                bf16x8 w3f = *reinterpret_cast<const bf16x8*>(&lds_w3A[net][half][lane4 + z4]);
                acc3 = MFMA(w3f, S.v, acc3);
            }
        }

        // ---- Euler update + store (rows 0,1 of acc3 on lanes 0-15) ----
        if (lo16) {
            float nya = fmaf(acc3[0], dt, ya);
            float nyb = fmaf(acc3[1], dt, yb);
            lds_y[wIdx][c][0] = nya;
            lds_y[wIdx][c][1] = nyb;
            int sample = waveG * 16 + c;
            reinterpret_cast<float2*>(out)[(size_t)s * BATCH + sample] =
                make_float2(nya, nyb);
        }
    }
}

extern "C" void kernel_launch(void* const* d_in, const int* in_sizes, int n_in,
                              void* d_out, int out_size, void* d_ws, size_t ws_size,
                              hipStream_t stream) {
    const float* y0  = (const float*)d_in[0];
    const float* tt  = (const float*)d_in[1];
    const float* fw1 = (const float*)d_in[2];
    const float* fb1 = (const float*)d_in[3];
    const float* fw2 = (const float*)d_in[4];
    const float* fb2 = (const float*)d_in[5];
    const float* fw3 = (const float*)d_in[6];
    const float* fb3 = (const float*)d_in[7];
    const float* gw1 = (const float*)d_in[8];
    const float* gb1 = (const float*)d_in[9];
    const float* gw2 = (const float*)d_in[10];
    const float* gb2 = (const float*)d_in[11];
    const float* gw3 = (const float*)d_in[12];
    const float* gb3 = (const float*)d_in[13];
    float* out = (float*)d_out;

    dim3 grid(512);    // 512 blocks x 8 waves = 4096 waves, 16 samples/wave
    dim3 block(512);   // 2 blocks/CU -> 16 waves/CU = 4 waves/SIMD
    hipLaunchKernelGGL(node_kernel, grid, block, 0, stream,
                       y0, tt, fw1, fb1, fw2, fb2, fw3, fb3,
                       gw1, gb1, gw2, gb2, gw3, gb3, out);
}

// Round 14
// 1914.448 us; speedup vs baseline: 3.1352x; 1.8349x over previous
//
#include <hip/hip_runtime.h>

#define BATCH 65536
#define T 500

typedef __attribute__((ext_vector_type(8))) short bf16x8;
typedef __attribute__((ext_vector_type(4))) float f32x4;

#define MFMA(A, B, C) __builtin_amdgcn_mfma_f32_16x16x32_bf16(A, B, C, 0, 0, 0)
#define PSEL 0x07060302u   // v_perm: low16 = hi16(srcB), high16 = hi16(srcA)

#define LOG2E 1.44269504088896340736f
#define LN2   0.693147180559945309417f

union U4 { unsigned u[4]; bf16x8 v; };

__device__ __forceinline__ float exp2_fast(float x) {
#if __has_builtin(__builtin_amdgcn_exp2f)
    return __builtin_amdgcn_exp2f(x);
#else
    float r; asm("v_exp_f32 %0, %1" : "=v"(r) : "v"(x)); return r;
#endif
}
__device__ __forceinline__ float log2_fast(float x) {
#if __has_builtin(__builtin_amdgcn_logf)
    return __builtin_amdgcn_logf(x);
#else
    float r; asm("v_log_f32 %0, %1" : "=v"(r) : "v"(x)); return r;
#endif
}

// d arrives pre-scaled by 2*log2e (folded into L1 weights): tanh core, 4 inst
__device__ __forceinline__ float tanh_act(float d) {
    return 1.0f - 2.0f * __builtin_amdgcn_rcpf(exp2_fast(d) + 1.0f);
}
// d arrives pre-scaled by log2e (folded into W2/b2); ln2 folded into w3: 3 inst
__device__ __forceinline__ float sp_act(float d) {
    return log2_fast(exp2_fast(d) + 1.0f);
}

// truncation split: hi = trunc_bf16(x) (exact top-16), lo = trunc_bf16(x - hi).
__device__ __forceinline__ void tsplit(float x, short& hs, short& ls) {
    unsigned uh = __float_as_uint(x) & 0xFFFF0000u;
    float r = x - __uint_as_float(uh);
    hs = (short)(uh >> 16);
    ls = (short)(__float_as_uint(r) >> 16);
}

// ---- layer-1 merged A-fragment (k-packed hi/lo/bias, one MFMA per tile) ----
//  k0..k7  (G=0): wa_h wb_h b_h wa_h wb_h wa_h wb_h wa_l
//  k8..k11 (G=1): wb_l wa_l wb_l b_l
// All entries pre-scaled by `scale` (activation fold), exact f32 mul.
__device__ __forceinline__ void build_l1(const float* __restrict__ W,
                                         const float* __restrict__ Bv,
                                         int Mreal, int t, int lane, float scale,
                                         bf16x8& A) {
    int row = t * 16 + (lane & 15);
    int G = lane >> 4;
    float wa = 0.f, wb = 0.f, bi = 0.f;
    if (row < Mreal) {
        wa = W[2 * row] * scale;
        wb = W[2 * row + 1] * scale;
        bi = Bv[row] * scale;
    }
    short wah, wal, wbh, wbl, bih, bil;
    tsplit(wa, wah, wal);
    tsplit(wb, wbh, wbl);
    tsplit(bi, bih, bil);
    #pragma unroll
    for (int j = 0; j < 8; ++j) A[j] = 0;
    if (G == 0) {
        A[0] = wah; A[1] = wbh; A[2] = bih; A[3] = wah;
        A[4] = wbh; A[5] = wah; A[6] = wbh; A[7] = wal;
    } else if (G == 1) {
        A[0] = wbl; A[1] = wal; A[2] = wbl; A[3] = bil;
    }
}

// ---- A-fragment split with k-PERMUTED axis, pre-scaled ----
// k-slot (u, G=lane>>4, j) holds hidden unit pi = 16*(2u + (j>>2)) + 4G + (j&3),
// so the D-registers of the previous layer ARE the B-frag (no redistribution).
__device__ __forceinline__ void build_frag_pi(const float* __restrict__ W,
                                              int Mreal, int Kreal, int Ks,
                                              int t, int u, int lane, float scale,
                                              bf16x8& hi, bf16x8& lo) {
    int row = t * 16 + (lane & 15);
    int G = lane >> 4;
    #pragma unroll
    for (int j = 0; j < 8; ++j) {
        int hidden = 16 * (2 * u + (j >> 2)) + 4 * G + (j & 3);
        float w = (row < Mreal && hidden < Kreal) ? W[row * Ks + hidden] * scale : 0.0f;
        short hs, ls;
        tsplit(w, hs, ls);
        hi[j] = hs; lo[j] = ls;
    }
}

// activation + trunc-bf16 pack of two D-tiles (2u, 2u+1) into one B k-frag.
template<bool TANH>
__device__ __forceinline__ U4 act_pack2(f32x4 dA, f32x4 dB) {
    float a0 = TANH ? tanh_act(dA[0]) : sp_act(dA[0]);
    float a1 = TANH ? tanh_act(dA[1]) : sp_act(dA[1]);
    float a2 = TANH ? tanh_act(dA[2]) : sp_act(dA[2]);
    float a3 = TANH ? tanh_act(dA[3]) : sp_act(dA[3]);
    float b0 = TANH ? tanh_act(dB[0]) : sp_act(dB[0]);
    float b1 = TANH ? tanh_act(dB[1]) : sp_act(dB[1]);
    float b2 = TANH ? tanh_act(dB[2]) : sp_act(dB[2]);
    float b3 = TANH ? tanh_act(dB[3]) : sp_act(dB[3]);
    U4 r;
    r.u[0] = __builtin_amdgcn_perm(__float_as_uint(a1), __float_as_uint(a0), PSEL);
    r.u[1] = __builtin_amdgcn_perm(__float_as_uint(a3), __float_as_uint(a2), PSEL);
    r.u[2] = __builtin_amdgcn_perm(__float_as_uint(b1), __float_as_uint(b0), PSEL);
    r.u[3] = __builtin_amdgcn_perm(__float_as_uint(b3), __float_as_uint(b2), PSEL);
    return r;
}

// y trunc 3-split -> k-packed B fragment (matches build_l1 k-slot table)
__device__ __forceinline__ void build_yB(float ya, float yb, int G, U4& yB) {
    unsigned ua = __float_as_uint(ya), ub = __float_as_uint(yb);
    unsigned uah = ua & 0xFFFF0000u;
    float ra = ya - __uint_as_float(uah);
    unsigned uam = __float_as_uint(ra) & 0xFFFF0000u;
    float ra2 = ra - __uint_as_float(uam);
    unsigned ubh = ub & 0xFFFF0000u;
    float rb = yb - __uint_as_float(ubh);
    unsigned ubm = __float_as_uint(rb) & 0xFFFF0000u;
    float rb2 = rb - __uint_as_float(ubm);

    unsigned w0g0 = __builtin_amdgcn_perm(ub, ua, PSEL);
    unsigned w1g0 = 0x00003F80u | uam;
    unsigned w2g0 = __builtin_amdgcn_perm(__float_as_uint(ra2), __float_as_uint(rb), PSEL);
    unsigned w3g0 = __builtin_amdgcn_perm(ua, __float_as_uint(rb2), PSEL);
    unsigned w0g1 = __builtin_amdgcn_perm(__float_as_uint(ra), ub, PSEL);
    unsigned w1g1 = (ubm >> 16) | 0x3F800000u;

    yB.u[0] = (G == 0) ? w0g0 : ((G == 1) ? w0g1 : 0u);
    yB.u[1] = (G == 0) ? w1g0 : ((G == 1) ? w1g1 : 0u);
    yB.u[2] = (G == 0) ? w2g0 : 0u;
    yB.u[3] = (G == 0) ? w3g0 : 0u;
}

__global__ void __launch_bounds__(512)
__attribute__((amdgpu_waves_per_eu(4, 4)))
node_kernel(const float* __restrict__ y0,
            const float* __restrict__ tt,
            const float* __restrict__ fw1, const float* __restrict__ fb1,
            const float* __restrict__ fw2, const float* __restrict__ fb2,
            const float* __restrict__ fw3, const float* __restrict__ fb3,
            const float* __restrict__ gw1, const float* __restrict__ gb1,
            const float* __restrict__ gw2, const float* __restrict__ gb2,
            const float* __restrict__ gw3, const float* __restrict__ gb3,
            float* __restrict__ out)
{
    // all weight fragments shared per block; acts live in registers
    __shared__ float lds_y[8][16][2];
    __shared__ __align__(16) float lds_b2[2][64];            // f,g L2 bias *log2e
    __shared__ __align__(16) unsigned lds_l1[2][4][256];     // merged L1 (pre-scaled)
    __shared__ __align__(16) unsigned lds_w2h[2][8][256];    // L2 hi frags (pi-k, *log2e)
    __shared__ __align__(16) unsigned lds_w2l[2][8][256];    // L2 lo frags (pi-k, *log2e)
    __shared__ __align__(16) unsigned lds_w3A[2][2][256];    // L3 hi frags (pi-k, *ln2)
    // total ~49.5 KB -> 2 blocks/CU, 16 waves/CU = 4 waves/SIMD

    const int lane  = threadIdx.x & 63;
    const int wIdx  = threadIdx.x >> 6;          // 0..7
    const int waveG = blockIdx.x * 8 + wIdx;     // 4096 waves
    const int c     = lane & 15;
    const int G     = lane >> 4;
    const bool lo16 = (lane < 16);
    const int lane4 = lane * 4;

    // block-shared tables (b2 pre-scaled by log2e for the exp2 softplus)
    if (threadIdx.x < 64) {
        int i = threadIdx.x;
        lds_b2[0][i] = fb2[i] * LOG2E;
        lds_b2[1][i] = (i < 52) ? gb2[i] * LOG2E : 0.0f;
    }

    // ---- build all weight fragments into LDS ----
    if (wIdx < 4) {
        const int t = wIdx;
        bf16x8 A, hi, lo;
        build_l1(fw1, fb1, 64, t, lane, 2.0f * LOG2E, A);
        *reinterpret_cast<bf16x8*>(&lds_l1[0][t][lane4]) = A;
        build_l1(gw1, gb1, 52, t, lane, 2.0f * LOG2E, A);
        *reinterpret_cast<bf16x8*>(&lds_l1[1][t][lane4]) = A;
        #pragma unroll
        for (int u = 0; u < 2; ++u) {
            build_frag_pi(fw2, 64, 64, 64, t, u, lane, LOG2E, hi, lo);
            *reinterpret_cast<bf16x8*>(&lds_w2h[0][2 * t + u][lane4]) = hi;
            *reinterpret_cast<bf16x8*>(&lds_w2l[0][2 * t + u][lane4]) = lo;
            build_frag_pi(gw2, 52, 52, 52, t, u, lane, LOG2E, hi, lo);
            *reinterpret_cast<bf16x8*>(&lds_w2h[1][2 * t + u][lane4]) = hi;
            *reinterpret_cast<bf16x8*>(&lds_w2l[1][2 * t + u][lane4]) = lo;
        }
    } else {
        const int net = (wIdx - 4) >> 1;         // 0=f, 1=g
        const int u   = (wIdx - 4) & 1;
        bf16x8 hi, lo;
        build_frag_pi(net ? gw3 : fw3, 2, net ? 52 : 64, net ? 52 : 64,
                      0, u, lane, LN2, hi, lo);
        *reinterpret_cast<bf16x8*>(&lds_w3A[net][u][lane4]) = hi;
    }
    __syncthreads();

    const float dt = tt[1] - tt[0];
    const float b3a = fb3[0] + gb3[0];
    const float b3b = fb3[1] + gb3[1];
    const f32x4 zero4 = {0.f, 0.f, 0.f, 0.f};

    // ---- y0 init (16 samples per wave) ----
    {
        int sample = waveG * 16 + c;
        if (lo16) {
            float2 yv = reinterpret_cast<const float2*>(y0)[sample];
            lds_y[wIdx][c][0] = yv.x;
            lds_y[wIdx][c][1] = yv.y;
            reinterpret_cast<float2*>(out)[sample] = yv;
        }
    }

    // ---- time loop ----
    #pragma unroll 1
    for (int s = 1; s < T; ++s) {
        // opaque zero index, redefined per iteration: blocks LICM/CSE from
        // hoisting weight-fragment loads into (spilled) registers.
        unsigned zoff = 0;
        asm volatile("" : "+v"(zoff));
        const unsigned z4 = zoff << 2;

        float ya = lds_y[wIdx][c][0];
        float yb = lds_y[wIdx][c][1];

        U4 yB;
        build_yB(ya, yb, G, yB);

        // layer-3 accumulator: D row 0 = out dim a, row 1 = out dim b (G==0)
        f32x4 acc3;
        acc3[0] = lo16 ? b3a : 0.f;
        acc3[1] = lo16 ? b3b : 0.f;
        acc3[2] = 0.f;
        acc3[3] = 0.f;

        #pragma unroll
        for (int net = 0; net < 2; ++net) {
            // layer 1: one MFMA per tile (output pre-scaled for tanh core)
            f32x4 d0, d1, d2, d3;
            {
                bf16x8 A0 = *reinterpret_cast<const bf16x8*>(&lds_l1[net][0][lane4 + z4]);
                bf16x8 A1 = *reinterpret_cast<const bf16x8*>(&lds_l1[net][1][lane4 + z4]);
                bf16x8 A2 = *reinterpret_cast<const bf16x8*>(&lds_l1[net][2][lane4 + z4]);
                bf16x8 A3 = *reinterpret_cast<const bf16x8*>(&lds_l1[net][3][lane4 + z4]);
                d0 = MFMA(A0, yB.v, zero4);
                d1 = MFMA(A1, yB.v, zero4);
                d2 = MFMA(A2, yB.v, zero4);
                d3 = MFMA(A3, yB.v, zero4);
            }
            U4 H0 = act_pack2<true>(d0, d1);
            U4 H1 = act_pack2<true>(d2, d3);

            // layer 2 (wh*H + wl*H, log2e-scaled) + layer-3 MFMA epilogue
            #pragma unroll
            for (int half = 0; half < 2; ++half) {
                f32x4 e[2];
                #pragma unroll
                for (int k = 0; k < 2; ++k) {
                    int t = 2 * half + k;
                    f32x4 a = *reinterpret_cast<const f32x4*>(&lds_b2[net][16 * t + 4 * G + z4]);
                    #pragma unroll
                    for (int u = 0; u < 2; ++u) {
                        bf16x8 wh = *reinterpret_cast<const bf16x8*>(&lds_w2h[net][2 * t + u][lane4 + z4]);
                        bf16x8 wl = *reinterpret_cast<const bf16x8*>(&lds_w2l[net][2 * t + u][lane4 + z4]);
                        a = MFMA(wh, u ? H1.v : H0.v, a);
                        a = MFMA(wl, u ? H1.v : H0.v, a);
                    }
                    e[k] = a;
                }
                U4 S = act_pack2<false>(e[0], e[1]);
                bf16x8 w3f = *reinterpret_cast<const bf16x8*>(&lds_w3A[net][half][lane4 + z4]);
                acc3 = MFMA(w3f, S.v, acc3);
            }
        }

        // ---- Euler update + store (rows 0,1 of acc3 on lanes 0-15) ----
        if (lo16) {
            float nya = fmaf(acc3[0], dt, ya);
            float nyb = fmaf(acc3[1], dt, yb);
            lds_y[wIdx][c][0] = nya;
            lds_y[wIdx][c][1] = nyb;
            int sample = waveG * 16 + c;
            reinterpret_cast<float2*>(out)[(size_t)s * BATCH + sample] =
                make_float2(nya, nyb);
        }
    }
}

extern "C" void kernel_launch(void* const* d_in, const int* in_sizes, int n_in,
                              void* d_out, int out_size, void* d_ws, size_t ws_size,
                              hipStream_t stream) {
    const float* y0  = (const float*)d_in[0];
    const float* tt  = (const float*)d_in[1];
    const float* fw1 = (const float*)d_in[2];
    const float* fb1 = (const float*)d_in[3];
    const float* fw2 = (const float*)d_in[4];
    const float* fb2 = (const float*)d_in[5];
    const float* fw3 = (const float*)d_in[6];
    const float* fb3 = (const float*)d_in[7];
    const float* gw1 = (const float*)d_in[8];
    const float* gb1 = (const float*)d_in[9];
    const float* gw2 = (const float*)d_in[10];
    const float* gb2 = (const float*)d_in[11];
    const float* gw3 = (const float*)d_in[12];
    const float* gb3 = (const float*)d_in[13];
    float* out = (float*)d_out;

    dim3 grid(512);    // 512 blocks x 8 waves = 4096 waves, 16 samples/wave
    dim3 block(512);   // 2 blocks/CU -> 16 waves/CU = 4 waves/SIMD
    hipLaunchKernelGGL(node_kernel, grid, block, 0, stream,
                       y0, tt, fw1, fb1, fw2, fb2, fw3, fb3,
                       gw1, gb1, gw2, gb2, gw3, gb3, out);
}

// Round 15
// 1889.980 us; speedup vs baseline: 3.1758x; 1.0129x over previous
//
#include <hip/hip_runtime.h>

#define BATCH 65536
#define T 500

typedef __attribute__((ext_vector_type(8))) short bf16x8;
typedef __attribute__((ext_vector_type(4))) float f32x4;

#define MFMA(A, B, C) __builtin_amdgcn_mfma_f32_16x16x32_bf16(A, B, C, 0, 0, 0)
#define PSEL 0x07060302u   // v_perm: low16 = hi16(srcB), high16 = hi16(srcA)

#define LOG2E 1.44269504088896340736f
#define LN2   0.693147180559945309417f

union U4 { unsigned u[4]; bf16x8 v; };

__device__ __forceinline__ float exp2_fast(float x) {
#if __has_builtin(__builtin_amdgcn_exp2f)
    return __builtin_amdgcn_exp2f(x);
#else
    float r; asm("v_exp_f32 %0, %1" : "=v"(r) : "v"(x)); return r;
#endif
}
__device__ __forceinline__ float log2_fast(float x) {
#if __has_builtin(__builtin_amdgcn_logf)
    return __builtin_amdgcn_logf(x);
#else
    float r; asm("v_log_f32 %0, %1" : "=v"(r) : "v"(x)); return r;
#endif
}

// d arrives pre-scaled by 2*log2e (folded into L1 weights): tanh core, 4 inst
__device__ __forceinline__ float tanh_act(float d) {
    return 1.0f - 2.0f * __builtin_amdgcn_rcpf(exp2_fast(d) + 1.0f);
}
// d arrives pre-scaled by log2e (folded into W2/b2); ln2 folded into w3: 3 inst
__device__ __forceinline__ float sp_act(float d) {
    return log2_fast(exp2_fast(d) + 1.0f);
}

// truncation split: hi = trunc_bf16(x) (exact top-16), lo = trunc_bf16(x - hi).
__device__ __forceinline__ void tsplit(float x, short& hs, short& ls) {
    unsigned uh = __float_as_uint(x) & 0xFFFF0000u;
    float r = x - __uint_as_float(uh);
    hs = (short)(uh >> 16);
    ls = (short)(__float_as_uint(r) >> 16);
}

// ---- layer-1 merged A-fragment (k-packed hi/lo/bias, one MFMA per tile) ----
//  k0..k7  (G=0): wa_h wb_h b_h wa_h wb_h wa_h wb_h wa_l
//  k8..k11 (G=1): wb_l wa_l wb_l b_l
// All entries pre-scaled by `scale` (activation fold), exact f32 mul.
__device__ __forceinline__ void build_l1(const float* __restrict__ W,
                                         const float* __restrict__ Bv,
                                         int Mreal, int t, int lane, float scale,
                                         bf16x8& A) {
    int row = t * 16 + (lane & 15);
    int G = lane >> 4;
    float wa = 0.f, wb = 0.f, bi = 0.f;
    if (row < Mreal) {
        wa = W[2 * row] * scale;
        wb = W[2 * row + 1] * scale;
        bi = Bv[row] * scale;
    }
    short wah, wal, wbh, wbl, bih, bil;
    tsplit(wa, wah, wal);
    tsplit(wb, wbh, wbl);
    tsplit(bi, bih, bil);
    #pragma unroll
    for (int j = 0; j < 8; ++j) A[j] = 0;
    if (G == 0) {
        A[0] = wah; A[1] = wbh; A[2] = bih; A[3] = wah;
        A[4] = wbh; A[5] = wah; A[6] = wbh; A[7] = wal;
    } else if (G == 1) {
        A[0] = wbl; A[1] = wal; A[2] = wbl; A[3] = bil;
    }
}

// ---- A-fragment split with k-PERMUTED axis, pre-scaled ----
// k-slot (u, G=lane>>4, j) holds hidden unit pi = 16*(2u + (j>>2)) + 4G + (j&3),
// so the D-registers of the previous layer ARE the B-frag (no redistribution).
__device__ __forceinline__ void build_frag_pi(const float* __restrict__ W,
                                              int Mreal, int Kreal, int Ks,
                                              int t, int u, int lane, float scale,
                                              bf16x8& hi, bf16x8& lo) {
    int row = t * 16 + (lane & 15);
    int G = lane >> 4;
    #pragma unroll
    for (int j = 0; j < 8; ++j) {
        int hidden = 16 * (2 * u + (j >> 2)) + 4 * G + (j & 3);
        float w = (row < Mreal && hidden < Kreal) ? W[row * Ks + hidden] * scale : 0.0f;
        short hs, ls;
        tsplit(w, hs, ls);
        hi[j] = hs; lo[j] = ls;
    }
}

// activation + trunc-bf16 pack of two D-tiles (2u, 2u+1) into one B k-frag.
template<bool TANH>
__device__ __forceinline__ U4 act_pack2(f32x4 dA, f32x4 dB) {
    float a0 = TANH ? tanh_act(dA[0]) : sp_act(dA[0]);
    float a1 = TANH ? tanh_act(dA[1]) : sp_act(dA[1]);
    float a2 = TANH ? tanh_act(dA[2]) : sp_act(dA[2]);
    float a3 = TANH ? tanh_act(dA[3]) : sp_act(dA[3]);
    float b0 = TANH ? tanh_act(dB[0]) : sp_act(dB[0]);
    float b1 = TANH ? tanh_act(dB[1]) : sp_act(dB[1]);
    float b2 = TANH ? tanh_act(dB[2]) : sp_act(dB[2]);
    float b3 = TANH ? tanh_act(dB[3]) : sp_act(dB[3]);
    U4 r;
    r.u[0] = __builtin_amdgcn_perm(__float_as_uint(a1), __float_as_uint(a0), PSEL);
    r.u[1] = __builtin_amdgcn_perm(__float_as_uint(a3), __float_as_uint(a2), PSEL);
    r.u[2] = __builtin_amdgcn_perm(__float_as_uint(b1), __float_as_uint(b0), PSEL);
    r.u[3] = __builtin_amdgcn_perm(__float_as_uint(b3), __float_as_uint(b2), PSEL);
    return r;
}

// y trunc 3-split -> k-packed B fragment (matches build_l1 k-slot table)
__device__ __forceinline__ void build_yB(float ya, float yb, int G, U4& yB) {
    unsigned ua = __float_as_uint(ya), ub = __float_as_uint(yb);
    unsigned uah = ua & 0xFFFF0000u;
    float ra = ya - __uint_as_float(uah);
    unsigned uam = __float_as_uint(ra) & 0xFFFF0000u;
    float ra2 = ra - __uint_as_float(uam);
    unsigned ubh = ub & 0xFFFF0000u;
    float rb = yb - __uint_as_float(ubh);
    unsigned ubm = __float_as_uint(rb) & 0xFFFF0000u;
    float rb2 = rb - __uint_as_float(ubm);

    unsigned w0g0 = __builtin_amdgcn_perm(ub, ua, PSEL);
    unsigned w1g0 = 0x00003F80u | uam;
    unsigned w2g0 = __builtin_amdgcn_perm(__float_as_uint(ra2), __float_as_uint(rb), PSEL);
    unsigned w3g0 = __builtin_amdgcn_perm(ua, __float_as_uint(rb2), PSEL);
    unsigned w0g1 = __builtin_amdgcn_perm(__float_as_uint(ra), ub, PSEL);
    unsigned w1g1 = (ubm >> 16) | 0x3F800000u;

    yB.u[0] = (G == 0) ? w0g0 : ((G == 1) ? w0g1 : 0u);
    yB.u[1] = (G == 0) ? w1g0 : ((G == 1) ? w1g1 : 0u);
    yB.u[2] = (G == 0) ? w2g0 : 0u;
    yB.u[3] = (G == 0) ? w3g0 : 0u;
}

__global__ void __launch_bounds__(512)
__attribute__((amdgpu_waves_per_eu(4, 4)))
node_kernel(const float* __restrict__ y0,
            const float* __restrict__ tt,
            const float* __restrict__ fw1, const float* __restrict__ fb1,
            const float* __restrict__ fw2, const float* __restrict__ fb2,
            const float* __restrict__ fw3, const float* __restrict__ fb3,
            const float* __restrict__ gw1, const float* __restrict__ gb1,
            const float* __restrict__ gw2, const float* __restrict__ gb2,
            const float* __restrict__ gw3, const float* __restrict__ gb3,
            float* __restrict__ out)
{
    // weight fragments shared per block; w2h promoted to persistent VGPRs
    __shared__ float lds_y[8][16][2];
    __shared__ __align__(16) float lds_b2[2][64];            // f,g L2 bias *log2e
    __shared__ __align__(16) unsigned lds_l1[2][4][256];     // merged L1 (pre-scaled)
    __shared__ __align__(16) unsigned lds_w2h[2][8][256];    // L2 hi frags (pi-k, *log2e)
    __shared__ __align__(16) unsigned lds_w2l[2][8][256];    // L2 lo frags (pi-k, *log2e)
    __shared__ __align__(16) unsigned lds_w3A[2][2][256];    // L3 hi frags (pi-k, *ln2)

    const int lane  = threadIdx.x & 63;
    const int wIdx  = threadIdx.x >> 6;          // 0..7
    const int waveG = blockIdx.x * 8 + wIdx;     // 4096 waves
    const int c     = lane & 15;
    const int G     = lane >> 4;
    const bool lo16 = (lane < 16);
    const int lane4 = lane * 4;

    // block-shared tables (b2 pre-scaled by log2e for the exp2 softplus)
    if (threadIdx.x < 64) {
        int i = threadIdx.x;
        lds_b2[0][i] = fb2[i] * LOG2E;
        lds_b2[1][i] = (i < 52) ? gb2[i] * LOG2E : 0.0f;
    }

    // ---- build all weight fragments into LDS ----
    if (wIdx < 4) {
        const int t = wIdx;
        bf16x8 A, hi, lo;
        build_l1(fw1, fb1, 64, t, lane, 2.0f * LOG2E, A);
        *reinterpret_cast<bf16x8*>(&lds_l1[0][t][lane4]) = A;
        build_l1(gw1, gb1, 52, t, lane, 2.0f * LOG2E, A);
        *reinterpret_cast<bf16x8*>(&lds_l1[1][t][lane4]) = A;
        #pragma unroll
        for (int u = 0; u < 2; ++u) {
            build_frag_pi(fw2, 64, 64, 64, t, u, lane, LOG2E, hi, lo);
            *reinterpret_cast<bf16x8*>(&lds_w2h[0][2 * t + u][lane4]) = hi;
            *reinterpret_cast<bf16x8*>(&lds_w2l[0][2 * t + u][lane4]) = lo;
            build_frag_pi(gw2, 52, 52, 52, t, u, lane, LOG2E, hi, lo);
            *reinterpret_cast<bf16x8*>(&lds_w2h[1][2 * t + u][lane4]) = hi;
            *reinterpret_cast<bf16x8*>(&lds_w2l[1][2 * t + u][lane4]) = lo;
        }
    } else {
        const int net = (wIdx - 4) >> 1;         // 0=f, 1=g
        const int u   = (wIdx - 4) & 1;
        bf16x8 hi, lo;
        build_frag_pi(net ? gw3 : fw3, 2, net ? 52 : 64, net ? 52 : 64,
                      0, u, lane, LN2, hi, lo);
        *reinterpret_cast<bf16x8*>(&lds_w3A[net][u][lane4]) = hi;
    }
    __syncthreads();

    // ---- persistent W2-hi fragments in registers (16 frags = 64 VGPR) ----
    // Loaded once, live for all 499 steps. NOT z4-opaqued: these are meant to
    // hoist. Total VGPR ~116 <= 128 keeps 4 waves/SIMD (R4/R5 lesson: audit!).
    bf16x8 w2hr[2][8];
    #pragma unroll
    for (int net = 0; net < 2; ++net)
        #pragma unroll
        for (int i = 0; i < 8; ++i)
            w2hr[net][i] = *reinterpret_cast<const bf16x8*>(&lds_w2h[net][i][lane4]);

    const float dt = tt[1] - tt[0];
    const float b3a = fb3[0] + gb3[0];
    const float b3b = fb3[1] + gb3[1];
    const f32x4 zero4 = {0.f, 0.f, 0.f, 0.f};

    // ---- y0 init (16 samples per wave) ----
    {
        int sample = waveG * 16 + c;
        if (lo16) {
            float2 yv = reinterpret_cast<const float2*>(y0)[sample];
            lds_y[wIdx][c][0] = yv.x;
            lds_y[wIdx][c][1] = yv.y;
            reinterpret_cast<float2*>(out)[sample] = yv;
        }
    }

    // ---- time loop ----
    #pragma unroll 1
    for (int s = 1; s < T; ++s) {
        // opaque zero index, redefined per iteration: blocks LICM/CSE from
        // hoisting the REMAINING LDS weight loads into (spilled) registers.
        unsigned zoff = 0;
        asm volatile("" : "+v"(zoff));
        const unsigned z4 = zoff << 2;

        float ya = lds_y[wIdx][c][0];
        float yb = lds_y[wIdx][c][1];

        U4 yB;
        build_yB(ya, yb, G, yB);

        // layer-3 accumulator: D row 0 = out dim a, row 1 = out dim b (G==0)
        f32x4 acc3;
        acc3[0] = lo16 ? b3a : 0.f;
        acc3[1] = lo16 ? b3b : 0.f;
        acc3[2] = 0.f;
        acc3[3] = 0.f;

        #pragma unroll
        for (int net = 0; net < 2; ++net) {
            // layer 1: one MFMA per tile (output pre-scaled for tanh core)
            f32x4 d0, d1, d2, d3;
            {
                bf16x8 A0 = *reinterpret_cast<const bf16x8*>(&lds_l1[net][0][lane4 + z4]);
                bf16x8 A1 = *reinterpret_cast<const bf16x8*>(&lds_l1[net][1][lane4 + z4]);
                bf16x8 A2 = *reinterpret_cast<const bf16x8*>(&lds_l1[net][2][lane4 + z4]);
                bf16x8 A3 = *reinterpret_cast<const bf16x8*>(&lds_l1[net][3][lane4 + z4]);
                d0 = MFMA(A0, yB.v, zero4);
                d1 = MFMA(A1, yB.v, zero4);
                d2 = MFMA(A2, yB.v, zero4);
                d3 = MFMA(A3, yB.v, zero4);
            }
            U4 H0 = act_pack2<true>(d0, d1);
            U4 H1 = act_pack2<true>(d2, d3);

            // layer 2 (w2h from REGISTERS, w2l from LDS) + layer-3 MFMA epilogue
            #pragma unroll
            for (int half = 0; half < 2; ++half) {
                f32x4 e[2];
                #pragma unroll
                for (int k = 0; k < 2; ++k) {
                    int t = 2 * half + k;
                    f32x4 a = *reinterpret_cast<const f32x4*>(&lds_b2[net][16 * t + 4 * G + z4]);
                    #pragma unroll
                    for (int u = 0; u < 2; ++u) {
                        bf16x8 wl = *reinterpret_cast<const bf16x8*>(&lds_w2l[net][2 * t + u][lane4 + z4]);
                        a = MFMA(w2hr[net][2 * t + u], u ? H1.v : H0.v, a);
                        a = MFMA(wl, u ? H1.v : H0.v, a);
                    }
                    e[k] = a;
                }
                U4 S = act_pack2<false>(e[0], e[1]);
                bf16x8 w3f = *reinterpret_cast<const bf16x8*>(&lds_w3A[net][half][lane4 + z4]);
                acc3 = MFMA(w3f, S.v, acc3);
            }
        }

        // ---- Euler update + store (rows 0,1 of acc3 on lanes 0-15) ----
        if (lo16) {
            float nya = fmaf(acc3[0], dt, ya);
            float nyb = fmaf(acc3[1], dt, yb);
            lds_y[wIdx][c][0] = nya;
            lds_y[wIdx][c][1] = nyb;
            int sample = waveG * 16 + c;
            reinterpret_cast<float2*>(out)[(size_t)s * BATCH + sample] =
                make_float2(nya, nyb);
        }
    }
}

extern "C" void kernel_launch(void* const* d_in, const int* in_sizes, int n_in,
                              void* d_out, int out_size, void* d_ws, size_t ws_size,
                              hipStream_t stream) {
    const float* y0  = (const float*)d_in[0];
    const float* tt  = (const float*)d_in[1];
    const float* fw1 = (const float*)d_in[2];
    const float* fb1 = (const float*)d_in[3];
    const float* fw2 = (const float*)d_in[4];
    const float* fb2 = (const float*)d_in[5];
    const float* fw3 = (const float*)d_in[6];
    const float* fb3 = (const float*)d_in[7];
    const float* gw1 = (const float*)d_in[8];
    const float* gb1 = (const float*)d_in[9];
    const float* gw2 = (const float*)d_in[10];
    const float* gb2 = (const float*)d_in[11];
    const float* gw3 = (const float*)d_in[12];
    const float* gb3 = (const float*)d_in[13];
    float* out = (float*)d_out;

    dim3 grid(512);    // 512 blocks x 8 waves = 4096 waves, 16 samples/wave
    dim3 block(512);   // 2 blocks/CU -> 16 waves/CU = 4 waves/SIMD
    hipLaunchKernelGGL(node_kernel, grid, block, 0, stream,
                       y0, tt, fw1, fb1, fw2, fb2, fw3, fb3,
                       gw1, gb1, gw2, gb2, gw3, gb3, out);
}

// Round 16
// 1887.980 us; speedup vs baseline: 3.1792x; 1.0011x over previous
//
#include <hip/hip_runtime.h>

#define BATCH 65536
#define T 500

typedef __attribute__((ext_vector_type(8))) short bf16x8;
typedef __attribute__((ext_vector_type(4))) float f32x4;

#define MFMA(A, B, C) __builtin_amdgcn_mfma_f32_16x16x32_bf16(A, B, C, 0, 0, 0)
#define PSEL 0x07060302u   // v_perm: low16 = hi16(srcB), high16 = hi16(srcA)

#define LOG2E 1.44269504088896340736f
#define LN2   0.693147180559945309417f

union U4 { unsigned u[4]; bf16x8 v; };

__device__ __forceinline__ float exp2_fast(float x) {
#if __has_builtin(__builtin_amdgcn_exp2f)
    return __builtin_amdgcn_exp2f(x);
#else
    float r; asm("v_exp_f32 %0, %1" : "=v"(r) : "v"(x)); return r;
#endif
}
__device__ __forceinline__ float log2_fast(float x) {
#if __has_builtin(__builtin_amdgcn_logf)
    return __builtin_amdgcn_logf(x);
#else
    float r; asm("v_log_f32 %0, %1" : "=v"(r) : "v"(x)); return r;
#endif
}

// d arrives pre-scaled by 2*log2e (folded into L1 weights): tanh core, 4 inst
__device__ __forceinline__ float tanh_act(float d) {
    return 1.0f - 2.0f * __builtin_amdgcn_rcpf(exp2_fast(d) + 1.0f);
}
// d arrives pre-scaled by log2e (folded into W2/b2); ln2 folded into w3: 3 inst
__device__ __forceinline__ float sp_act(float d) {
    return log2_fast(exp2_fast(d) + 1.0f);
}

// truncation split: hi = trunc_bf16(x) (exact top-16), lo = trunc_bf16(x - hi).
__device__ __forceinline__ void tsplit(float x, short& hs, short& ls) {
    unsigned uh = __float_as_uint(x) & 0xFFFF0000u;
    float r = x - __uint_as_float(uh);
    hs = (short)(uh >> 16);
    ls = (short)(__float_as_uint(r) >> 16);
}

// ---- layer-1 merged A-fragment (k-packed hi/lo/bias, one MFMA per tile) ----
//  k0..k7  (G=0): wa_h wb_h b_h wa_h wb_h wa_h wb_h wa_l
//  k8..k11 (G=1): wb_l wa_l wb_l b_l
// All entries pre-scaled by `scale` (activation fold), exact f32 mul.
__device__ __forceinline__ void build_l1(const float* __restrict__ W,
                                         const float* __restrict__ Bv,
                                         int Mreal, int t, int lane, float scale,
                                         bf16x8& A) {
    int row = t * 16 + (lane & 15);
    int G = lane >> 4;
    float wa = 0.f, wb = 0.f, bi = 0.f;
    if (row < Mreal) {
        wa = W[2 * row] * scale;
        wb = W[2 * row + 1] * scale;
        bi = Bv[row] * scale;
    }
    short wah, wal, wbh, wbl, bih, bil;
    tsplit(wa, wah, wal);
    tsplit(wb, wbh, wbl);
    tsplit(bi, bih, bil);
    #pragma unroll
    for (int j = 0; j < 8; ++j) A[j] = 0;
    if (G == 0) {
        A[0] = wah; A[1] = wbh; A[2] = bih; A[3] = wah;
        A[4] = wbh; A[5] = wah; A[6] = wbh; A[7] = wal;
    } else if (G == 1) {
        A[0] = wbl; A[1] = wal; A[2] = wbl; A[3] = bil;
    }
}

// ---- A-fragment split with k-PERMUTED axis, pre-scaled ----
// k-slot (u, G=lane>>4, j) holds hidden unit pi = 16*(2u + (j>>2)) + 4G + (j&3),
// so the D-registers of the previous layer ARE the B-frag (no redistribution).
__device__ __forceinline__ void build_frag_pi(const float* __restrict__ W,
                                              int Mreal, int Kreal, int Ks,
                                              int t, int u, int lane, float scale,
                                              bf16x8& hi, bf16x8& lo) {
    int row = t * 16 + (lane & 15);
    int G = lane >> 4;
    #pragma unroll
    for (int j = 0; j < 8; ++j) {
        int hidden = 16 * (2 * u + (j >> 2)) + 4 * G + (j & 3);
        float w = (row < Mreal && hidden < Kreal) ? W[row * Ks + hidden] * scale : 0.0f;
        short hs, ls;
        tsplit(w, hs, ls);
        hi[j] = hs; lo[j] = ls;
    }
}

// activation + trunc-bf16 pack of two D-tiles (2u, 2u+1) into one B k-frag.
template<bool TANH>
__device__ __forceinline__ U4 act_pack2(f32x4 dA, f32x4 dB) {
    float a0 = TANH ? tanh_act(dA[0]) : sp_act(dA[0]);
    float a1 = TANH ? tanh_act(dA[1]) : sp_act(dA[1]);
    float a2 = TANH ? tanh_act(dA[2]) : sp_act(dA[2]);
    float a3 = TANH ? tanh_act(dA[3]) : sp_act(dA[3]);
    float b0 = TANH ? tanh_act(dB[0]) : sp_act(dB[0]);
    float b1 = TANH ? tanh_act(dB[1]) : sp_act(dB[1]);
    float b2 = TANH ? tanh_act(dB[2]) : sp_act(dB[2]);
    float b3 = TANH ? tanh_act(dB[3]) : sp_act(dB[3]);
    U4 r;
    r.u[0] = __builtin_amdgcn_perm(__float_as_uint(a1), __float_as_uint(a0), PSEL);
    r.u[1] = __builtin_amdgcn_perm(__float_as_uint(a3), __float_as_uint(a2), PSEL);
    r.u[2] = __builtin_amdgcn_perm(__float_as_uint(b1), __float_as_uint(b0), PSEL);
    r.u[3] = __builtin_amdgcn_perm(__float_as_uint(b3), __float_as_uint(b2), PSEL);
    return r;
}

// y trunc 3-split -> k-packed B fragment (matches build_l1 k-slot table)
__device__ __forceinline__ void build_yB(float ya, float yb, int G, U4& yB) {
    unsigned ua = __float_as_uint(ya), ub = __float_as_uint(yb);
    unsigned uah = ua & 0xFFFF0000u;
    float ra = ya - __uint_as_float(uah);
    unsigned uam = __float_as_uint(ra) & 0xFFFF0000u;
    float ra2 = ra - __uint_as_float(uam);
    unsigned ubh = ub & 0xFFFF0000u;
    float rb = yb - __uint_as_float(ubh);
    unsigned ubm = __float_as_uint(rb) & 0xFFFF0000u;
    float rb2 = rb - __uint_as_float(ubm);

    unsigned w0g0 = __builtin_amdgcn_perm(ub, ua, PSEL);
    unsigned w1g0 = 0x00003F80u | uam;
    unsigned w2g0 = __builtin_amdgcn_perm(__float_as_uint(ra2), __float_as_uint(rb), PSEL);
    unsigned w3g0 = __builtin_amdgcn_perm(ua, __float_as_uint(rb2), PSEL);
    unsigned w0g1 = __builtin_amdgcn_perm(__float_as_uint(ra), ub, PSEL);
    unsigned w1g1 = (ubm >> 16) | 0x3F800000u;

    yB.u[0] = (G == 0) ? w0g0 : ((G == 1) ? w0g1 : 0u);
    yB.u[1] = (G == 0) ? w1g0 : ((G == 1) ? w1g1 : 0u);
    yB.u[2] = (G == 0) ? w2g0 : 0u;
    yB.u[3] = (G == 0) ? w3g0 : 0u;
}

__global__ void __launch_bounds__(512)
__attribute__((amdgpu_waves_per_eu(4, 4)))
node_kernel(const float* __restrict__ y0,
            const float* __restrict__ tt,
            const float* __restrict__ fw1, const float* __restrict__ fb1,
            const float* __restrict__ fw2, const float* __restrict__ fb2,
            const float* __restrict__ fw3, const float* __restrict__ fb3,
            const float* __restrict__ gw1, const float* __restrict__ gb1,
            const float* __restrict__ gw2, const float* __restrict__ gb2,
            const float* __restrict__ gw3, const float* __restrict__ gb3,
            float* __restrict__ out)
{
    // weight fragments shared per block; w2h pinned into persistent VGPRs
    __shared__ float lds_y[8][16][2];
    __shared__ __align__(16) float lds_b2[2][64];            // f,g L2 bias *log2e
    __shared__ __align__(16) unsigned lds_l1[2][4][256];     // merged L1 (pre-scaled)
    __shared__ __align__(16) unsigned lds_w2h[2][8][256];    // L2 hi frags (pi-k, *log2e)
    __shared__ __align__(16) unsigned lds_w2l[2][8][256];    // L2 lo frags (pi-k, *log2e)
    __shared__ __align__(16) unsigned lds_w3A[2][2][256];    // L3 hi frags (pi-k, *ln2)

    const int lane  = threadIdx.x & 63;
    const int wIdx  = threadIdx.x >> 6;          // 0..7
    const int waveG = blockIdx.x * 8 + wIdx;     // 4096 waves
    const int c     = lane & 15;
    const int G     = lane >> 4;
    const bool lo16 = (lane < 16);
    const int lane4 = lane * 4;

    // block-shared tables (b2 pre-scaled by log2e for the exp2 softplus)
    if (threadIdx.x < 64) {
        int i = threadIdx.x;
        lds_b2[0][i] = fb2[i] * LOG2E;
        lds_b2[1][i] = (i < 52) ? gb2[i] * LOG2E : 0.0f;
    }

    // ---- build all weight fragments into LDS ----
    if (wIdx < 4) {
        const int t = wIdx;
        bf16x8 A, hi, lo;
        build_l1(fw1, fb1, 64, t, lane, 2.0f * LOG2E, A);
        *reinterpret_cast<bf16x8*>(&lds_l1[0][t][lane4]) = A;
        build_l1(gw1, gb1, 52, t, lane, 2.0f * LOG2E, A);
        *reinterpret_cast<bf16x8*>(&lds_l1[1][t][lane4]) = A;
        #pragma unroll
        for (int u = 0; u < 2; ++u) {
            build_frag_pi(fw2, 64, 64, 64, t, u, lane, LOG2E, hi, lo);
            *reinterpret_cast<bf16x8*>(&lds_w2h[0][2 * t + u][lane4]) = hi;
            *reinterpret_cast<bf16x8*>(&lds_w2l[0][2 * t + u][lane4]) = lo;
            build_frag_pi(gw2, 52, 52, 52, t, u, lane, LOG2E, hi, lo);
            *reinterpret_cast<bf16x8*>(&lds_w2h[1][2 * t + u][lane4]) = hi;
            *reinterpret_cast<bf16x8*>(&lds_w2l[1][2 * t + u][lane4]) = lo;
        }
    } else {
        const int net = (wIdx - 4) >> 1;         // 0=f, 1=g
        const int u   = (wIdx - 4) & 1;
        bf16x8 hi, lo;
        build_frag_pi(net ? gw3 : fw3, 2, net ? 52 : 64, net ? 52 : 64,
                      0, u, lane, LN2, hi, lo);
        *reinterpret_cast<bf16x8*>(&lds_w3A[net][u][lane4]) = hi;
    }
    __syncthreads();

    // ---- persistent W2-hi fragments, FORCE-pinned in registers ----
    // R15 lesson: plain pre-loop LDS loads get rematerialized (VGPR stayed 56).
    // The opaque asm redefines each fragment, making re-load from LDS illegal:
    // the 16 fragments (64 VGPR) must stay live. Budget: ~56 + 64 = ~120 <= 128.
    bf16x8 w2hr[2][8];
    #pragma unroll
    for (int net = 0; net < 2; ++net) {
        #pragma unroll
        for (int i = 0; i < 8; ++i) {
            w2hr[net][i] = *reinterpret_cast<const bf16x8*>(&lds_w2h[net][i][lane4]);
            asm volatile("" : "+v"(w2hr[net][i]));
        }
    }

    const float dt = tt[1] - tt[0];
    const float b3a = fb3[0] + gb3[0];
    const float b3b = fb3[1] + gb3[1];
    const f32x4 zero4 = {0.f, 0.f, 0.f, 0.f};

    // ---- y0 init (16 samples per wave) ----
    {
        int sample = waveG * 16 + c;
        if (lo16) {
            float2 yv = reinterpret_cast<const float2*>(y0)[sample];
            lds_y[wIdx][c][0] = yv.x;
            lds_y[wIdx][c][1] = yv.y;
            reinterpret_cast<float2*>(out)[sample] = yv;
        }
    }

    // ---- time loop ----
    #pragma unroll 1
    for (int s = 1; s < T; ++s) {
        // opaque zero index, redefined per iteration: blocks LICM/CSE from
        // hoisting the REMAINING LDS weight loads into (spilled) registers.
        unsigned zoff = 0;
        asm volatile("" : "+v"(zoff));
        const unsigned z4 = zoff << 2;

        float ya = lds_y[wIdx][c][0];
        float yb = lds_y[wIdx][c][1];

        U4 yB;
        build_yB(ya, yb, G, yB);

        // layer-3 accumulator: D row 0 = out dim a, row 1 = out dim b (G==0)
        f32x4 acc3;
        acc3[0] = lo16 ? b3a : 0.f;
        acc3[1] = lo16 ? b3b : 0.f;
        acc3[2] = 0.f;
        acc3[3] = 0.f;

        #pragma unroll
        for (int net = 0; net < 2; ++net) {
            // layer 1: one MFMA per tile (output pre-scaled for tanh core)
            f32x4 d0, d1, d2, d3;
            {
                bf16x8 A0 = *reinterpret_cast<const bf16x8*>(&lds_l1[net][0][lane4 + z4]);
                bf16x8 A1 = *reinterpret_cast<const bf16x8*>(&lds_l1[net][1][lane4 + z4]);
                bf16x8 A2 = *reinterpret_cast<const bf16x8*>(&lds_l1[net][2][lane4 + z4]);
                bf16x8 A3 = *reinterpret_cast<const bf16x8*>(&lds_l1[net][3][lane4 + z4]);
                d0 = MFMA(A0, yB.v, zero4);
                d1 = MFMA(A1, yB.v, zero4);
                d2 = MFMA(A2, yB.v, zero4);
                d3 = MFMA(A3, yB.v, zero4);
            }
            U4 H0 = act_pack2<true>(d0, d1);
            U4 H1 = act_pack2<true>(d2, d3);

            // layer 2 (w2h from PINNED REGISTERS, w2l from LDS) + L3 epilogue
            #pragma unroll
            for (int half = 0; half < 2; ++half) {
                f32x4 e[2];
                #pragma unroll
                for (int k = 0; k < 2; ++k) {
                    int t = 2 * half + k;
                    f32x4 a = *reinterpret_cast<const f32x4*>(&lds_b2[net][16 * t + 4 * G + z4]);
                    #pragma unroll
                    for (int u = 0; u < 2; ++u) {
                        bf16x8 wl = *reinterpret_cast<const bf16x8*>(&lds_w2l[net][2 * t + u][lane4 + z4]);
                        a = MFMA(w2hr[net][2 * t + u], u ? H1.v : H0.v, a);
                        a = MFMA(wl, u ? H1.v : H0.v, a);
                    }
                    e[k] = a;
                }
                U4 S = act_pack2<false>(e[0], e[1]);
                bf16x8 w3f = *reinterpret_cast<const bf16x8*>(&lds_w3A[net][half][lane4 + z4]);
                acc3 = MFMA(w3f, S.v, acc3);
            }
        }

        // ---- Euler update + store (rows 0,1 of acc3 on lanes 0-15) ----
        if (lo16) {
            float nya = fmaf(acc3[0], dt, ya);
            float nyb = fmaf(acc3[1], dt, yb);
            lds_y[wIdx][c][0] = nya;
            lds_y[wIdx][c][1] = nyb;
            int sample = waveG * 16 + c;
            reinterpret_cast<float2*>(out)[(size_t)s * BATCH + sample] =
                make_float2(nya, nyb);
        }
    }
}

extern "C" void kernel_launch(void* const* d_in, const int* in_sizes, int n_in,
                              void* d_out, int out_size, void* d_ws, size_t ws_size,
                              hipStream_t stream) {
    const float* y0  = (const float*)d_in[0];
    const float* tt  = (const float*)d_in[1];
    const float* fw1 = (const float*)d_in[2];
    const float* fb1 = (const float*)d_in[3];
    const float* fw2 = (const float*)d_in[4];
    const float* fb2 = (const float*)d_in[5];
    const float* fw3 = (const float*)d_in[6];
    const float* fb3 = (const float*)d_in[7];
    const float* gw1 = (const float*)d_in[8];
    const float* gb1 = (const float*)d_in[9];
    const float* gw2 = (const float*)d_in[10];
    const float* gb2 = (const float*)d_in[11];
    const float* gw3 = (const float*)d_in[12];
    const float* gb3 = (const float*)d_in[13];
    float* out = (float*)d_out;

    dim3 grid(512);    // 512 blocks x 8 waves = 4096 waves, 16 samples/wave
    dim3 block(512);   // 2 blocks/CU -> 16 waves/CU = 4 waves/SIMD
    hipLaunchKernelGGL(node_kernel, grid, block, 0, stream,
                       y0, tt, fw1, fb1, fw2, fb2, fw3, fb3,
                       gw1, gb1, gw2, gb2, gw3, gb3, out);
}

// Round 17
// 1877.696 us; speedup vs baseline: 3.1966x; 1.0055x over previous
//
#include <hip/hip_runtime.h>

#define BATCH 65536
#define T 500

typedef __attribute__((ext_vector_type(8))) short bf16x8;
typedef __attribute__((ext_vector_type(4))) float f32x4;

#define MFMA(A, B, C) __builtin_amdgcn_mfma_f32_16x16x32_bf16(A, B, C, 0, 0, 0)
#define PSEL 0x07060302u   // v_perm: low16 = hi16(srcB), high16 = hi16(srcA)

#define LOG2E 1.44269504088896340736f
#define LN2   0.693147180559945309417f

union U4 { unsigned u[4]; bf16x8 v; };

__device__ __forceinline__ float exp2_fast(float x) {
#if __has_builtin(__builtin_amdgcn_exp2f)
    return __builtin_amdgcn_exp2f(x);
#else
    float r; asm("v_exp_f32 %0, %1" : "=v"(r) : "v"(x)); return r;
#endif
}
__device__ __forceinline__ float log2_fast(float x) {
#if __has_builtin(__builtin_amdgcn_logf)
    return __builtin_amdgcn_logf(x);
#else
    float r; asm("v_log_f32 %0, %1" : "=v"(r) : "v"(x)); return r;
#endif
}

// d arrives pre-scaled by 2*log2e (folded into L1 weights): tanh core, 4 inst
__device__ __forceinline__ float tanh_act(float d) {
    return 1.0f - 2.0f * __builtin_amdgcn_rcpf(exp2_fast(d) + 1.0f);
}
// d arrives pre-scaled by log2e (folded into W2/b2); ln2 folded into w3: 3 inst
__device__ __forceinline__ float sp_act(float d) {
    return log2_fast(exp2_fast(d) + 1.0f);
}

// truncation split: hi = trunc_bf16(x) (exact top-16), lo = trunc_bf16(x - hi).
__device__ __forceinline__ void tsplit(float x, short& hs, short& ls) {
    unsigned uh = __float_as_uint(x) & 0xFFFF0000u;
    float r = x - __uint_as_float(uh);
    hs = (short)(uh >> 16);
    ls = (short)(__float_as_uint(r) >> 16);
}

// ---- layer-1 merged A-fragment: 2-level y-split layout ----
// G0 k0..k7: waH wbH bH waH wbH waL wbL bL   (G1..G3: zero)
// paired with yB G0: yaH ybH 1.0 yaM ybM yaH ybH 1.0
// All entries pre-scaled by `scale` (activation fold), exact f32 mul.
__device__ __forceinline__ void build_l1(const float* __restrict__ W,
                                         const float* __restrict__ Bv,
                                         int Mreal, int t, int lane, float scale,
                                         bf16x8& A) {
    int row = t * 16 + (lane & 15);
    int G = lane >> 4;
    float wa = 0.f, wb = 0.f, bi = 0.f;
    if (row < Mreal) {
        wa = W[2 * row] * scale;
        wb = W[2 * row + 1] * scale;
        bi = Bv[row] * scale;
    }
    short wah, wal, wbh, wbl, bih, bil;
    tsplit(wa, wah, wal);
    tsplit(wb, wbh, wbl);
    tsplit(bi, bih, bil);
    #pragma unroll
    for (int j = 0; j < 8; ++j) A[j] = 0;
    if (G == 0) {
        A[0] = wah; A[1] = wbh; A[2] = bih; A[3] = wah;
        A[4] = wbh; A[5] = wal; A[6] = wbl; A[7] = bil;
    }
}

// ---- A-fragment split with k-PERMUTED axis, pre-scaled ----
// k-slot (u, G=lane>>4, j) holds hidden unit pi = 16*(2u + (j>>2)) + 4G + (j&3),
// so the D-registers of the previous layer ARE the B-frag (no redistribution).
__device__ __forceinline__ void build_frag_pi(const float* __restrict__ W,
                                              int Mreal, int Kreal, int Ks,
                                              int t, int u, int lane, float scale,
                                              bf16x8& hi, bf16x8& lo) {
    int row = t * 16 + (lane & 15);
    int G = lane >> 4;
    #pragma unroll
    for (int j = 0; j < 8; ++j) {
        int hidden = 16 * (2 * u + (j >> 2)) + 4 * G + (j & 3);
        float w = (row < Mreal && hidden < Kreal) ? W[row * Ks + hidden] * scale : 0.0f;
        short hs, ls;
        tsplit(w, hs, ls);
        hi[j] = hs; lo[j] = ls;
    }
}

// activation + trunc-bf16 pack of two D-tiles (2u, 2u+1) into one B k-frag.
template<bool TANH>
__device__ __forceinline__ U4 act_pack2(f32x4 dA, f32x4 dB) {
    float a0 = TANH ? tanh_act(dA[0]) : sp_act(dA[0]);
    float a1 = TANH ? tanh_act(dA[1]) : sp_act(dA[1]);
    float a2 = TANH ? tanh_act(dA[2]) : sp_act(dA[2]);
    float a3 = TANH ? tanh_act(dA[3]) : sp_act(dA[3]);
    float b0 = TANH ? tanh_act(dB[0]) : sp_act(dB[0]);
    float b1 = TANH ? tanh_act(dB[1]) : sp_act(dB[1]);
    float b2 = TANH ? tanh_act(dB[2]) : sp_act(dB[2]);
    float b3 = TANH ? tanh_act(dB[3]) : sp_act(dB[3]);
    U4 r;
    r.u[0] = __builtin_amdgcn_perm(__float_as_uint(a1), __float_as_uint(a0), PSEL);
    r.u[1] = __builtin_amdgcn_perm(__float_as_uint(a3), __float_as_uint(a2), PSEL);
    r.u[2] = __builtin_amdgcn_perm(__float_as_uint(b1), __float_as_uint(b0), PSEL);
    r.u[3] = __builtin_amdgcn_perm(__float_as_uint(b3), __float_as_uint(b2), PSEL);
    return r;
}

// y trunc 2-SPLIT -> k-packed B fragment (matches build_l1 k-slot table).
// y enters L1 with 16 mantissa bits: error 2^-17|y| per step — negligible.
__device__ __forceinline__ void build_yB(float ya, float yb, int G, U4& yB) {
    unsigned ua = __float_as_uint(ya), ub = __float_as_uint(yb);
    unsigned uah = ua & 0xFFFF0000u;
    float ra = ya - __uint_as_float(uah);
    unsigned ubh = ub & 0xFFFF0000u;
    float rb = yb - __uint_as_float(ubh);

    unsigned w0 = __builtin_amdgcn_perm(ub, ua, PSEL);                  // yaH|ybH
    unsigned w1 = 0x00003F80u | (__float_as_uint(ra) & 0xFFFF0000u);    // 1.0|yaM
    unsigned w2 = __builtin_amdgcn_perm(ua, __float_as_uint(rb), PSEL); // ybM|yaH
    unsigned w3 = (ubh >> 16) | 0x3F800000u;                            // ybH|1.0

    bool g0 = (G == 0);
    yB.u[0] = g0 ? w0 : 0u;
    yB.u[1] = g0 ? w1 : 0u;
    yB.u[2] = g0 ? w2 : 0u;
    yB.u[3] = g0 ? w3 : 0u;
}

__global__ void __launch_bounds__(512)
__attribute__((amdgpu_waves_per_eu(4, 4)))
node_kernel(const float* __restrict__ y0,
            const float* __restrict__ tt,
            const float* __restrict__ fw1, const float* __restrict__ fb1,
            const float* __restrict__ fw2, const float* __restrict__ fb2,
            const float* __restrict__ fw3, const float* __restrict__ fb3,
            const float* __restrict__ gw1, const float* __restrict__ gb1,
            const float* __restrict__ gw2, const float* __restrict__ gb2,
            const float* __restrict__ gw3, const float* __restrict__ gb3,
            float* __restrict__ out)
{
    // all weight fragments shared per block; y state lives in registers
    __shared__ __align__(16) float lds_b2[2][64];            // f,g L2 bias *log2e
    __shared__ __align__(16) unsigned lds_l1[2][4][256];     // merged L1 (pre-scaled)
    __shared__ __align__(16) unsigned lds_w2h[2][8][256];    // L2 hi frags (pi-k, *log2e)
    __shared__ __align__(16) unsigned lds_w2l[2][8][256];    // L2 lo frags (pi-k, *log2e)
    __shared__ __align__(16) unsigned lds_w3A[2][2][256];    // L3 hi frags (pi-k, *ln2)

    const int lane  = threadIdx.x & 63;
    const int wIdx  = threadIdx.x >> 6;          // 0..7
    const int waveG = blockIdx.x * 8 + wIdx;     // 4096 waves
    const int c     = lane & 15;
    const int G     = lane >> 4;
    const bool lo16 = (lane < 16);
    const int lane4 = lane * 4;

    // block-shared tables (b2 pre-scaled by log2e for the exp2 softplus)
    if (threadIdx.x < 64) {
        int i = threadIdx.x;
        lds_b2[0][i] = fb2[i] * LOG2E;
        lds_b2[1][i] = (i < 52) ? gb2[i] * LOG2E : 0.0f;
    }

    // ---- build all weight fragments into LDS ----
    if (wIdx < 4) {
        const int t = wIdx;
        bf16x8 A, hi, lo;
        build_l1(fw1, fb1, 64, t, lane, 2.0f * LOG2E, A);
        *reinterpret_cast<bf16x8*>(&lds_l1[0][t][lane4]) = A;
        build_l1(gw1, gb1, 52, t, lane, 2.0f * LOG2E, A);
        *reinterpret_cast<bf16x8*>(&lds_l1[1][t][lane4]) = A;
        #pragma unroll
        for (int u = 0; u < 2; ++u) {
            build_frag_pi(fw2, 64, 64, 64, t, u, lane, LOG2E, hi, lo);
            *reinterpret_cast<bf16x8*>(&lds_w2h[0][2 * t + u][lane4]) = hi;
            *reinterpret_cast<bf16x8*>(&lds_w2l[0][2 * t + u][lane4]) = lo;
            build_frag_pi(gw2, 52, 52, 52, t, u, lane, LOG2E, hi, lo);
            *reinterpret_cast<bf16x8*>(&lds_w2h[1][2 * t + u][lane4]) = hi;
            *reinterpret_cast<bf16x8*>(&lds_w2l[1][2 * t + u][lane4]) = lo;
        }
    } else {
        const int net = (wIdx - 4) >> 1;         // 0=f, 1=g
        const int u   = (wIdx - 4) & 1;
        bf16x8 hi, lo;
        build_frag_pi(net ? gw3 : fw3, 2, net ? 52 : 64, net ? 52 : 64,
                      0, u, lane, LN2, hi, lo);
        *reinterpret_cast<bf16x8*>(&lds_w3A[net][u][lane4]) = hi;
    }
    __syncthreads();

    const float dt = tt[1] - tt[0];
    const float b3a = fb3[0] + gb3[0];
    const float b3b = fb3[1] + gb3[1];
    const f32x4 zero4 = {0.f, 0.f, 0.f, 0.f};

    // ---- y0 init: y state in REGISTERS on all lanes (broadcast read) ----
    float ya, yb;
    {
        int sample = waveG * 16 + c;
        float2 yv = reinterpret_cast<const float2*>(y0)[sample];
        ya = yv.x; yb = yv.y;
        if (lo16) reinterpret_cast<float2*>(out)[sample] = yv;
    }

    // ---- time loop ----
    #pragma unroll 1
    for (int s = 1; s < T; ++s) {
        // opaque zero index, redefined per iteration: blocks LICM/CSE from
        // hoisting the LDS weight loads into (spilled) registers.
        unsigned zoff = 0;
        asm volatile("" : "+v"(zoff));
        const unsigned z4 = zoff << 2;

        U4 yB;
        build_yB(ya, yb, G, yB);

        // layer-3 accumulator: D row 0 = out dim a, row 1 = out dim b (G==0)
        f32x4 acc3;
        acc3[0] = lo16 ? b3a : 0.f;
        acc3[1] = lo16 ? b3b : 0.f;
        acc3[2] = 0.f;
        acc3[3] = 0.f;

        #pragma unroll
        for (int net = 0; net < 2; ++net) {
            // layer 1: one MFMA per tile (output pre-scaled for tanh core)
            f32x4 d0, d1, d2, d3;
            {
                bf16x8 A0 = *reinterpret_cast<const bf16x8*>(&lds_l1[net][0][lane4 + z4]);
                bf16x8 A1 = *reinterpret_cast<const bf16x8*>(&lds_l1[net][1][lane4 + z4]);
                bf16x8 A2 = *reinterpret_cast<const bf16x8*>(&lds_l1[net][2][lane4 + z4]);
                bf16x8 A3 = *reinterpret_cast<const bf16x8*>(&lds_l1[net][3][lane4 + z4]);
                d0 = MFMA(A0, yB.v, zero4);
                d1 = MFMA(A1, yB.v, zero4);
                d2 = MFMA(A2, yB.v, zero4);
                d3 = MFMA(A3, yB.v, zero4);
            }
            U4 H0 = act_pack2<true>(d0, d1);
            U4 H1 = act_pack2<true>(d2, d3);

            // layer 2 (wh*H + wl*H, log2e-scaled) + layer-3 MFMA epilogue
            #pragma unroll
            for (int half = 0; half < 2; ++half) {
                f32x4 e[2];
                #pragma unroll
                for (int k = 0; k < 2; ++k) {
                    int t = 2 * half + k;
                    f32x4 a = *reinterpret_cast<const f32x4*>(&lds_b2[net][16 * t + 4 * G + z4]);
                    #pragma unroll
                    for (int u = 0; u < 2; ++u) {
                        bf16x8 wh = *reinterpret_cast<const bf16x8*>(&lds_w2h[net][2 * t + u][lane4 + z4]);
                        bf16x8 wl = *reinterpret_cast<const bf16x8*>(&lds_w2l[net][2 * t + u][lane4 + z4]);
                        a = MFMA(wh, u ? H1.v : H0.v, a);
                        a = MFMA(wl, u ? H1.v : H0.v, a);
                    }
                    e[k] = a;
                }
                U4 S = act_pack2<false>(e[0], e[1]);
                bf16x8 w3f = *reinterpret_cast<const bf16x8*>(&lds_w3A[net][half][lane4 + z4]);
                acc3 = MFMA(w3f, S.v, acc3);
            }
        }

        // ---- Euler update in registers + shfl broadcast (no LDS round-trip) ----
        float nya = fmaf(acc3[0], dt, ya);   // valid on lanes 0-15 (G==0)
        float nyb = fmaf(acc3[1], dt, yb);
        if (lo16) {
            int sample = waveG * 16 + c;
            reinterpret_cast<float2*>(out)[(size_t)s * BATCH + sample] =
                make_float2(nya, nyb);
        }
        ya = __shfl(nya, c);   // broadcast sample c's state to all 4 groups
        yb = __shfl(nyb, c);
    }
}

extern "C" void kernel_launch(void* const* d_in, const int* in_sizes, int n_in,
                              void* d_out, int out_size, void* d_ws, size_t ws_size,
                              hipStream_t stream) {
    const float* y0  = (const float*)d_in[0];
    const float* tt  = (const float*)d_in[1];
    const float* fw1 = (const float*)d_in[2];
    const float* fb1 = (const float*)d_in[3];
    const float* fw2 = (const float*)d_in[4];
    const float* fb2 = (const float*)d_in[5];
    const float* fw3 = (const float*)d_in[6];
    const float* fb3 = (const float*)d_in[7];
    const float* gw1 = (const float*)d_in[8];
    const float* gb1 = (const float*)d_in[9];
    const float* gw2 = (const float*)d_in[10];
    const float* gb2 = (const float*)d_in[11];
    const float* gw3 = (const float*)d_in[12];
    const float* gb3 = (const float*)d_in[13];
    float* out = (float*)d_out;

    dim3 grid(512);    // 512 blocks x 8 waves = 4096 waves, 16 samples/wave
    dim3 block(512);   // 2 blocks/CU -> 16 waves/CU = 4 waves/SIMD
    hipLaunchKernelGGL(node_kernel, grid, block, 0, stream,
                       y0, tt, fw1, fb1, fw2, fb2, fw3, fb3,
                       gw1, gb1, gw2, gb2, gw3, gb3, out);
}